// Round 4
// baseline (1102.946 us; speedup 1.0000x reference)
//
#include <hip/hip_runtime.h>
#include <stdint.h>

#define DEVI __device__ __forceinline__

typedef unsigned short u16;
typedef short s8v __attribute__((ext_vector_type(8)));
typedef float f4v __attribute__((ext_vector_type(4)));
typedef u16 u16x4 __attribute__((ext_vector_type(4)));

DEVI u16 f2bf(float f) {
  unsigned u = __float_as_uint(f);
  u += 0x7fffu + ((u >> 16) & 1u);
  return (u16)(u >> 16);
}
DEVI float bf2f(u16 h) { return __uint_as_float(((unsigned)h) << 16); }

DEVI void gload16(const void* g, void* l) {
  __builtin_amdgcn_global_load_lds(
      (const __attribute__((address_space(1))) void*)(uintptr_t)g,
      (__attribute__((address_space(3))) void*)(uintptr_t)l, 16, 0, 0);
}

// ---------------- transpose + f32->bf16 convert: W[R][C] -> Wt[C][R] ----------
__global__ __launch_bounds__(256) void transpose_w(const float* __restrict__ W,
                                                   u16* __restrict__ Wt, int R, int C) {
  __shared__ float tile[32][33];
  const int tx = threadIdx.x & 31, ty = threadIdx.x >> 5;
  const int r0 = blockIdx.y * 32, c0 = blockIdx.x * 32;
#pragma unroll
  for (int i = 0; i < 4; ++i)
    tile[ty + 8 * i][tx] = W[(size_t)(r0 + ty + 8 * i) * C + c0 + tx];
  __syncthreads();
#pragma unroll
  for (int i = 0; i < 4; ++i)
    Wt[(size_t)(c0 + ty + 8 * i) * R + r0 + tx] = f2bf(tile[tx][ty + 8 * i]);
}

// ------- row LayerNorm (D=1024), f32 in -> bf16 out; optionally zero zbuf[row]
__global__ __launch_bounds__(256) void ln_rows(const float* __restrict__ x,
                                               const float* __restrict__ g,
                                               const float* __restrict__ bsh,
                                               u16* __restrict__ y,
                                               float* __restrict__ zbuf) {
  const size_t row = blockIdx.x;
  const int t = threadIdx.x;
  if (zbuf && t == 0) zbuf[row] = 0.f;
  float4 v = ((const float4*)(x + row * 1024))[t];
  float s = v.x + v.y + v.z + v.w;
  float q = v.x * v.x + v.y * v.y + v.z * v.z + v.w * v.w;
#pragma unroll
  for (int m = 1; m < 64; m <<= 1) { s += __shfl_xor(s, m); q += __shfl_xor(q, m); }
  __shared__ float sh[8];
  if ((t & 63) == 0) { sh[t >> 6] = s; sh[4 + (t >> 6)] = q; }
  __syncthreads();
  s = sh[0] + sh[1] + sh[2] + sh[3];
  q = sh[4] + sh[5] + sh[6] + sh[7];
  const float mu = s * (1.f / 1024.f);
  const float var = q * (1.f / 1024.f) - mu * mu;
  const float rs = rsqrtf(var + 1e-5f);
  const int c = t * 4;
  const float in[4] = {v.x, v.y, v.z, v.w};
  u16x4 o;
#pragma unroll
  for (int i = 0; i < 4; ++i) o[i] = f2bf((in[i] - mu) * rs * g[c + i] + bsh[c + i]);
  *(u16x4*)(y + row * 1024 + c) = o;
}

// ============ 256x256 MFMA GEMM, BK=32, 4-slot LDS ring, counted vmcnt =======
// C[M,N] = A[M,K] @ Bt[N,K]^T.  512 threads (8 waves = 2M x 4N), per-wave C
// block 128x64, acc[8][4] f32x4.  LDS ring: 4 slots x (A 16KB + B 16KB).
// ONE barrier per tile: staging slot (T+3)&3 holds tile T-1 whose ds_reads
// retired before each wave's T-1 MFMAs consumed them (register dependence),
// i.e. before this barrier -> post-barrier writes cannot race reads.
// Staging UNCONDITIONAL with clamped tile index => 4 issues/iter/wave; at top
// of iter T issued = 12+4T, vmcnt(8) => completed >= 4T+4 => tile T resident
// (own loads); barrier makes it collective across waves.
// LDS k-slot XOR swizzle (T2, both-sides): data for k-block kq of row r lives
// at slot kq^((r>>1)&3).  Read: slot lane-constant kx. Write: gload_lds dest
// stays LINEAR; the per-lane GLOBAL column is pre-swizzled (rule 21).
// => each consecutive-lane octet of a ds_read_b128 hits all 8 bank groups.
// EPI 0: fused KV epilogue (col0<1024 -> K-path w/ rowssq+gain, else V-path)
// EPI 1: CK bf16 = gelu_exact(acc + biasK[col]), ldc = N.
template <int EPI>
__global__ __launch_bounds__(512, 2) void gemm256(
    const u16* __restrict__ A, const u16* __restrict__ Bt,
    const float* __restrict__ biasK, const float* __restrict__ biasV,
    const float* __restrict__ gcol, u16* __restrict__ CK, u16* __restrict__ CV,
    float* __restrict__ rowssq, int M, int N, int K, int RB, int CB) {
  __shared__ u16 lds[4][16384];  // per slot: A tile [256][32] then B tile [256][32]
  const int t = threadIdx.x;
  const int lane = t & 63;
  const int wave = t >> 6;
  const int wm = wave >> 2, wn = wave & 3;
  const int fr = lane & 15, kq = lane >> 4;

  // XCD-aware swizzle (gridDim.x % 8 == 0 for all our shapes)
  const int bid = blockIdx.x;
  const int cpx = gridDim.x >> 3;
  const int swz = (bid & 7) * cpx + (bid >> 3);
  const int rb = swz / CB, cb = swz % CB;  // cb-fastest
  const size_t row0 = (size_t)rb * 256, col0 = (size_t)cb * 256;

  f4v acc[8][4];
#pragma unroll
  for (int i = 0; i < 8; ++i)
#pragma unroll
    for (int n = 0; n < 4; ++n) acc[i][n] = (f4v){0.f, 0.f, 0.f, 0.f};

  // staging: thread t writes LDS linear (dest = half-base + t*16B); global
  // column pre-swizzled so slot s of row r holds k-block s^((r>>1)&3).
  const int srow = t >> 2;
  const int scol = (((t & 3) ^ ((t >> 3) & 3)) << 3);
  const u16* Ag0 = A + (row0 + srow) * (size_t)K + scol;
  const u16* Ag1 = Ag0 + (size_t)128 * K;
  const u16* Bg0 = Bt + (col0 + srow) * (size_t)K + scol;
  const u16* Bg1 = Bg0 + (size_t)128 * K;

  // read-side swizzled k-slot; rows are m*16+fr based so (row>>1)&3 == (fr>>1)&3
  const int kx = ((kq ^ ((fr >> 1) & 3)) << 3);

  const int NT = K >> 5;  // BK=32; requires NT >= 4 (K >= 128)

  // prologue: stage tiles 0..2 (12 loads; 4 per tile)
#pragma unroll
  for (int tt = 0; tt < 3; ++tt) {
    u16* sA = &lds[tt][0];
    u16* sB = &lds[tt][8192];
    gload16(Ag0 + tt * 32, sA + t * 8);
    gload16(Ag1 + tt * 32, sA + 4096 + t * 8);
    gload16(Bg0 + tt * 32, sB + t * 8);
    gload16(Bg1 + tt * 32, sB + 4096 + t * 8);
  }

#pragma unroll 4
  for (int T = 0; T < NT; ++T) {
    asm volatile("s_waitcnt vmcnt(8)" ::: "memory");
    __builtin_amdgcn_s_barrier();
    __builtin_amdgcn_sched_barrier(0);
    const u16* sA = &lds[T & 3][0];
    const u16* sB = &lds[T & 3][8192];
    const int Ts = (T + 3 < NT) ? T + 3 : NT - 1;  // clamp: uniform issue count
    s8v a0[4], a1[4], b[4];
#pragma unroll
    for (int m = 0; m < 4; ++m)
      a0[m] = *(const s8v*)&sA[(wm * 128 + m * 16 + fr) * 32 + kx];
#pragma unroll
    for (int n = 0; n < 4; ++n)
      b[n] = *(const s8v*)&sB[(wn * 64 + n * 16 + fr) * 32 + kx];
#pragma unroll
    for (int m = 0; m < 4; ++m)
      a1[m] = *(const s8v*)&sA[(wm * 128 + 64 + m * 16 + fr) * 32 + kx];
    {
      u16* dA = &lds[(T + 3) & 3][0];  // holds tile T-1: reads done pre-barrier
      u16* dB = &lds[(T + 3) & 3][8192];
      gload16(Ag0 + Ts * 32, dA + t * 8);
      gload16(Ag1 + Ts * 32, dA + 4096 + t * 8);
      gload16(Bg0 + Ts * 32, dB + t * 8);
      gload16(Bg1 + Ts * 32, dB + 4096 + t * 8);
    }
    __builtin_amdgcn_s_setprio(1);
#pragma unroll
    for (int m = 0; m < 4; ++m)
#pragma unroll
      for (int n = 0; n < 4; ++n)
        acc[m][n] = __builtin_amdgcn_mfma_f32_16x16x32_bf16(a0[m], b[n], acc[m][n], 0, 0, 0);
#pragma unroll
    for (int m = 0; m < 4; ++m)
#pragma unroll
      for (int n = 0; n < 4; ++n)
        acc[4 + m][n] = __builtin_amdgcn_mfma_f32_16x16x32_bf16(a1[m], b[n], acc[4 + m][n], 0, 0, 0);
    __builtin_amdgcn_s_setprio(0);
  }

  // ---- epilogue ----
  const int kq4 = kq * 4;
  if (EPI == 0) {
    const bool isK = (col0 < 1024);
    if (isK) {
#pragma unroll
      for (int ai = 0; ai < 8; ++ai) {
        int cols[4];
        float bb[4], gg[4];
#pragma unroll
        for (int n = 0; n < 4; ++n) {
          cols[n] = (int)col0 + wn * 64 + n * 16 + fr;
          bb[n] = biasK[cols[n]];
          gg[n] = gcol[cols[n]];
        }
#pragma unroll
        for (int r = 0; r < 4; ++r) {
          const size_t grow = row0 + wm * 128 + ai * 16 + kq4 + r;
          float v[4];
#pragma unroll
          for (int n = 0; n < 4; ++n) v[n] = acc[ai][n][r] + bb[n];
          float s = v[0] * v[0] + v[1] * v[1] + v[2] * v[2] + v[3] * v[3];
          s += __shfl_xor(s, 1);
          s += __shfl_xor(s, 2);
          s += __shfl_xor(s, 4);
          s += __shfl_xor(s, 8);
          if (fr == 0) atomicAdd(&rowssq[grow], s);
#pragma unroll
          for (int n = 0; n < 4; ++n)
            CK[grow * 1024 + cols[n]] = f2bf(v[n] * gg[n]);
        }
      }
    } else {
#pragma unroll
      for (int ai = 0; ai < 8; ++ai) {
        int cols[4];
        float bb[4];
#pragma unroll
        for (int n = 0; n < 4; ++n) {
          cols[n] = (int)col0 - 1024 + wn * 64 + n * 16 + fr;
          bb[n] = biasV[cols[n]];
        }
#pragma unroll
        for (int r = 0; r < 4; ++r) {
          const size_t grow = row0 + wm * 128 + ai * 16 + kq4 + r;
#pragma unroll
          for (int n = 0; n < 4; ++n)
            CV[grow * 1024 + cols[n]] = f2bf(acc[ai][n][r] + bb[n]);
        }
      }
    }
  } else {
#pragma unroll
    for (int ai = 0; ai < 8; ++ai) {
      int cols[4];
      float bb[4];
#pragma unroll
      for (int n = 0; n < 4; ++n) {
        cols[n] = (int)col0 + wn * 64 + n * 16 + fr;
        bb[n] = biasK[cols[n]];
      }
#pragma unroll
      for (int r = 0; r < 4; ++r) {
        const size_t grow = row0 + wm * 128 + ai * 16 + kq4 + r;
#pragma unroll
        for (int n = 0; n < 4; ++n) {
          const float x = acc[ai][n][r] + bb[n];
          CK[grow * (size_t)N + cols[n]] = f2bf(0.5f * x * (1.f + erff(x * 0.70710678118654752f)));
        }
      }
    }
  }
}

// ---------------- 128x128 MFMA GEMM (m97 structure), epilogues ---------------
// Same T2 swizzle: linear LDS dest, pre-swizzled global col, lane-const kx.
// EPI 3: store f32 (acc+bias+extra[row,col])
// EPI 5: v=acc+bias; atomic rowssq += v^2; store bf16 v   (q-path)
// EPI 6: split-K partial: store f32 raw acc to Cv + z*M*N; K-range by blockIdx.z
template <int EPI>
__global__ __launch_bounds__(256) void gemm_bt(
    const u16* __restrict__ A, const u16* __restrict__ Bt,
    const float* __restrict__ bias, const float* __restrict__ gcol,
    void* __restrict__ Cv, const float* __restrict__ extra,
    float* __restrict__ rowssq, int M, int N, int K) {
  __shared__ u16 As[128 * 32];
  __shared__ u16 Bs[128 * 32];
  const int t = threadIdx.x;
  const int lane = t & 63;
  const int wave = t >> 6;
  const int wr = wave >> 1, wc = wave & 1;
  const size_t row0 = (size_t)blockIdx.y * 128;
  const size_t col0 = (size_t)blockIdx.x * 128;
  int Ksub = K, koff = 0;
  if (EPI == 6) { Ksub = K / gridDim.z; koff = blockIdx.z * Ksub; }

  f4v acc[4][4];
#pragma unroll
  for (int m = 0; m < 4; ++m)
#pragma unroll
    for (int n = 0; n < 4; ++n) acc[m][n] = (f4v){0.f, 0.f, 0.f, 0.f};

  const int sr = t >> 2;
  const int scw = (((t & 3) ^ ((t >> 3) & 3)) << 3);  // pre-swizzled global col
  const u16* Ag = A + (row0 + sr) * (size_t)K + koff + scw;
  const u16* Bg = Bt + (col0 + sr) * (size_t)K + koff + scw;
  u16* Al = &As[t * 8];  // linear dest
  u16* Bl = &Bs[t * 8];
  const int fr = lane & 15;
  const int kx = (((lane >> 4) ^ ((fr >> 1) & 3)) << 3);

  for (int k0 = 0; k0 < Ksub; k0 += 32) {
    gload16(Ag + k0, Al);
    gload16(Ag + k0 + (size_t)64 * K, Al + 64 * 32);
    gload16(Bg + k0, Bl);
    gload16(Bg + k0 + (size_t)64 * K, Bl + 64 * 32);
    __syncthreads();
    s8v a[4], b[4];
#pragma unroll
    for (int m = 0; m < 4; ++m)
      a[m] = *(const s8v*)&As[(wr * 64 + m * 16 + fr) * 32 + kx];
#pragma unroll
    for (int n = 0; n < 4; ++n)
      b[n] = *(const s8v*)&Bs[(wc * 64 + n * 16 + fr) * 32 + kx];
#pragma unroll
    for (int m = 0; m < 4; ++m)
#pragma unroll
      for (int n = 0; n < 4; ++n)
        acc[m][n] = __builtin_amdgcn_mfma_f32_16x16x32_bf16(a[m], b[n], acc[m][n], 0, 0, 0);
    __syncthreads();
  }

  float* Cp = (float*)Cv;
  if (EPI == 6) Cp += (size_t)blockIdx.z * M * (size_t)N;
  const int rg = (lane >> 4) * 4;
#pragma unroll
  for (int m = 0; m < 4; ++m) {
    int cols[4];
    float bvals[4];
#pragma unroll
    for (int n = 0; n < 4; ++n) {
      cols[n] = (int)col0 + wc * 64 + n * 16 + fr;
      bvals[n] = (EPI == 6) ? 0.f : bias[cols[n]];
    }
#pragma unroll
    for (int r = 0; r < 4; ++r) {
      const size_t grow = row0 + wr * 64 + m * 16 + rg + r;
      float v[4];
#pragma unroll
      for (int n = 0; n < 4; ++n) v[n] = acc[m][n][r] + bvals[n];
      if (EPI == 5) {
        float s = v[0] * v[0] + v[1] * v[1] + v[2] * v[2] + v[3] * v[3];
        s += __shfl_xor(s, 1);
        s += __shfl_xor(s, 2);
        s += __shfl_xor(s, 4);
        s += __shfl_xor(s, 8);
        if (fr == 0) atomicAdd(&rowssq[grow], s);
      }
#pragma unroll
      for (int n = 0; n < 4; ++n) {
        const size_t idx = grow * (size_t)N + cols[n];
        if (EPI == 3) {
          Cp[idx] = v[n] + extra[idx];
        } else if (EPI == 5) {
          ((u16*)Cv)[idx] = f2bf(v[n]);
        } else if (EPI == 6) {
          Cp[idx] = v[n];
        }
      }
    }
  }
}

// ---------------- attention with the faithful raw-reshape semantics ----------
// head h, key j in [0,32): kv position = 2h + j/16, d-slice = (j%16)*64 .. +64
// q applied here: q_eff[d] = qpre[d]*gq[d]*rsq_q*0.125 (rms of q folded)
__global__ __launch_bounds__(256) void attn_k(const u16* __restrict__ qf,
                                              const u16* __restrict__ kmat,
                                              const float* __restrict__ kssq,
                                              const u16* __restrict__ vmat,
                                              const float* __restrict__ gq,
                                              const float* __restrict__ qssq,
                                              u16* __restrict__ ao) {
  const int lb = blockIdx.x;
  const int t = threadIdx.x;
  const int wave = t >> 6, lane = t & 63;
  const int j = lane & 31, half = lane >> 5;
  const float rq = rsqrtf(qssq[lb] * (1.f / 1024.f) + 1e-6f) * 0.125f;
  __shared__ float po[64][17];
#pragma unroll
  for (int hi = 0; hi < 4; ++hi) {
    const int h = wave * 4 + hi;
    const int krow = lb * 32 + 2 * h + (j >> 4);
    const u16* kp = kmat + (size_t)krow * 1024 + (j & 15) * 64 + half * 32;
    const u16* qp = qf + (size_t)lb * 1024 + h * 64 + half * 32;
    const float* gqp = gq + h * 64 + half * 32;
    float s = 0.f;
#pragma unroll
    for (int cc = 0; cc < 4; ++cc) {
      s8v qv = *(const s8v*)(qp + cc * 8);
      s8v kv = *(const s8v*)(kp + cc * 8);
#pragma unroll
      for (int e = 0; e < 8; ++e)
        s += bf2f((u16)qv[e]) * gqp[cc * 8 + e] * bf2f((u16)kv[e]);
    }
    s += __shfl_xor(s, 32);
    s *= rsqrtf(kssq[krow] * (1.f / 1024.f) + 1e-6f) * rq;
    float mx = s;
#pragma unroll
    for (int m = 16; m >= 1; m >>= 1) mx = fmaxf(mx, __shfl_xor(mx, m));
    const float pe = __expf(s - mx);
    float sum = pe;
#pragma unroll
    for (int m = 16; m >= 1; m >>= 1) sum += __shfl_xor(sum, m);
    const float pr = pe / sum;
    float o = 0.f;
#pragma unroll
    for (int jj = 0; jj < 32; ++jj) {
      const int vrow = lb * 32 + 2 * h + (jj >> 4);
      const float vv = bf2f(vmat[(size_t)vrow * 1024 + (jj & 15) * 64 + lane]);
      o += __shfl(pr, jj) * vv;
    }
    po[lane][h] = o;  // hd = lane
  }
  __syncthreads();
  const int c = t * 4;
  u16x4 o4;
#pragma unroll
  for (int i = 0; i < 4; ++i) o4[i] = f2bf(po[(c + i) >> 4][(c + i) & 15]);
  *(u16x4*)(ao + (size_t)lb * 1024 + c) = o4;
}

// ------------- W2 split-K combine: out = p0 + p1 + b2[col] + resid -----------
__global__ __launch_bounds__(256) void combine_k(const float* __restrict__ p0,
                                                 const float* __restrict__ p1,
                                                 const float* __restrict__ b2,
                                                 const float* __restrict__ resid,
                                                 float* __restrict__ out) {
  const int i = blockIdx.x * 256 + threadIdx.x;  // float4 index
  float4 a = ((const float4*)p0)[i];
  float4 b = ((const float4*)p1)[i];
  float4 r = ((const float4*)resid)[i];
  float4 bb = ((const float4*)b2)[i & 255];
  float4 o;
  o.x = a.x + b.x + r.x + bb.x;
  o.y = a.y + b.y + r.y + bb.y;
  o.z = a.z + b.z + r.z + bb.z;
  o.w = a.w + b.w + r.w + bb.w;
  ((float4*)out)[i] = o;
}

// -----------------------------------------------------------------------------
extern "C" void kernel_launch(void* const* d_in, const int* in_sizes, int n_in,
                              void* d_out, int out_size, void* d_ws, size_t ws_size,
                              hipStream_t stream) {
  const float* query  = (const float*)d_in[0];
  const float* pf     = (const float*)d_in[1];
  const float* lnq_g  = (const float*)d_in[2];
  const float* lnq_b  = (const float*)d_in[3];
  const float* lnkv_g = (const float*)d_in[4];
  const float* lnkv_b = (const float*)d_in[5];
  const float* Wq     = (const float*)d_in[6];
  const float* bq     = (const float*)d_in[7];
  const float* Wk     = (const float*)d_in[8];
  const float* bk     = (const float*)d_in[9];
  const float* Wv     = (const float*)d_in[10];
  const float* bv     = (const float*)d_in[11];
  const float* rmsq_g = (const float*)d_in[12];
  const float* rmsk_g = (const float*)d_in[13];
  const float* Wo     = (const float*)d_in[14];
  const float* bo     = (const float*)d_in[15];
  const float* mlpn_g = (const float*)d_in[16];
  const float* mlpn_b = (const float*)d_in[17];
  const float* W1     = (const float*)d_in[18];
  const float* b1     = (const float*)d_in[19];
  const float* W2     = (const float*)d_in[20];
  const float* b2     = (const float*)d_in[21];
  float* out = (float*)d_out;

  char* p = (char*)d_ws;
  auto alloc = [&](size_t n) {
    char* r = p;
    p += (n + 255) & ~(size_t)255;
    return r;
  };

  u16* Wqt = (u16*)alloc((size_t)1024 * 1024 * 2);
  u16* KVt = (u16*)alloc((size_t)2048 * 1024 * 2);  // [Wk^T ; Wv^T]
  u16* Wot = (u16*)alloc((size_t)1024 * 1024 * 2);
  u16* W1t = (u16*)alloc((size_t)1024 * 4096 * 2);
  u16* W2t = (u16*)alloc((size_t)4096 * 1024 * 2);
  u16* qln = (u16*)alloc((size_t)4096 * 1024 * 2);
  u16* qpre = (u16*)alloc((size_t)4096 * 1024 * 2);
  float* qssq = (float*)alloc((size_t)4096 * 4);
  u16* attn_o = (u16*)alloc((size_t)4096 * 1024 * 2);
  float* outbuf = (float*)alloc((size_t)4096 * 1024 * 4);
  u16* hbuf = (u16*)alloc((size_t)4096 * 1024 * 2);
  u16* mid = (u16*)alloc((size_t)4096 * 4096 * 2);
  float* w2p = (float*)alloc((size_t)2 * 4096 * 1024 * 4);  // split-K partials
  const size_t ROWS = 131072;
  u16* kvln = (u16*)alloc(ROWS * 2048);
  u16* kmat = (u16*)alloc(ROWS * 2048);
  u16* vmat = (u16*)alloc(ROWS * 2048);
  float* kssq = (float*)alloc(ROWS * 4);

  // weight transpose+convert: W[K][N] f32 -> Wt[N][K] bf16
  transpose_w<<<dim3(32, 32), 256, 0, stream>>>(Wq, Wqt, 1024, 1024);
  transpose_w<<<dim3(32, 32), 256, 0, stream>>>(Wk, KVt, 1024, 1024);
  transpose_w<<<dim3(32, 32), 256, 0, stream>>>(Wv, KVt + (size_t)1024 * 1024, 1024, 1024);
  transpose_w<<<dim3(32, 32), 256, 0, stream>>>(Wo, Wot, 1024, 1024);
  transpose_w<<<dim3(128, 32), 256, 0, stream>>>(W1, W1t, 1024, 4096);
  transpose_w<<<dim3(32, 128), 256, 0, stream>>>(W2, W2t, 4096, 1024);

  // q path: LN -> GEMM(Wq)+bq (epilogue: bf16 qpre + qssq atomics)
  ln_rows<<<4096, 256, 0, stream>>>(query, lnq_g, lnq_b, qln, qssq);
  gemm_bt<5><<<dim3(8, 32), 256, 0, stream>>>(qln, Wqt, bq, nullptr, qpre, nullptr,
                                              qssq, 4096, 1024, 1024);

  // kv path: full-size LN, single fused K+V GEMM, single attn
  ln_rows<<<(unsigned)ROWS, 256, 0, stream>>>(pf, lnkv_g, lnkv_b, kvln, kssq);
  gemm256<0><<<512 * 8, 512, 0, stream>>>(kvln, KVt, bk, bv, rmsk_g, kmat, vmat,
                                          kssq, (int)ROWS, 2048, 1024, 512, 8);
  attn_k<<<4096, 256, 0, stream>>>(qpre, kmat, kssq, vmat, rmsq_g, qssq, attn_o);

  // out = attn_o @ Wo + bo + query  (f32)
  gemm_bt<3><<<dim3(8, 32), 256, 0, stream>>>(attn_o, Wot, bo, nullptr, outbuf, query,
                                              nullptr, 4096, 1024, 1024);
  // h = LN(out)
  ln_rows<<<4096, 256, 0, stream>>>(outbuf, mlpn_g, mlpn_b, hbuf, nullptr);
  // mid = gelu(h @ W1 + b1)  -- 256^2 kernel, grid 16x16
  gemm256<1><<<16 * 16, 512, 0, stream>>>(hbuf, W1t, b1, nullptr, nullptr, mid, nullptr,
                                          nullptr, 4096, 4096, 1024, 16, 16);
  // final = mid @ W2 (split-K=2 partials) + b2 + out
  gemm_bt<6><<<dim3(8, 32, 2), 256, 0, stream>>>(mid, W2t, nullptr, nullptr, w2p,
                                                 nullptr, nullptr, 4096, 1024, 4096);
  combine_k<<<4096, 256, 0, stream>>>(w2p, w2p + (size_t)4096 * 1024, b2, outbuf, out);
}

// Round 5
// 1092.515 us; speedup vs baseline: 1.0095x; 1.0095x over previous
//
#include <hip/hip_runtime.h>
#include <stdint.h>

#define DEVI __device__ __forceinline__

typedef unsigned short u16;
typedef short s8v __attribute__((ext_vector_type(8)));
typedef float f4v __attribute__((ext_vector_type(4)));
typedef u16 u16x4 __attribute__((ext_vector_type(4)));

DEVI u16 f2bf(float f) {
  unsigned u = __float_as_uint(f);
  u += 0x7fffu + ((u >> 16) & 1u);
  return (u16)(u >> 16);
}
DEVI float bf2f(u16 h) { return __uint_as_float(((unsigned)h) << 16); }

DEVI void gload16(const void* g, void* l) {
  __builtin_amdgcn_global_load_lds(
      (const __attribute__((address_space(1))) void*)(uintptr_t)g,
      (__attribute__((address_space(3))) void*)(uintptr_t)l, 16, 0, 0);
}

// ---------------- transpose + f32->bf16 convert: W[R][C] -> Wt[C][R] ----------
__global__ __launch_bounds__(256) void transpose_w(const float* __restrict__ W,
                                                   u16* __restrict__ Wt, int R, int C) {
  __shared__ float tile[32][33];
  const int tx = threadIdx.x & 31, ty = threadIdx.x >> 5;
  const int r0 = blockIdx.y * 32, c0 = blockIdx.x * 32;
#pragma unroll
  for (int i = 0; i < 4; ++i)
    tile[ty + 8 * i][tx] = W[(size_t)(r0 + ty + 8 * i) * C + c0 + tx];
  __syncthreads();
#pragma unroll
  for (int i = 0; i < 4; ++i)
    Wt[(size_t)(c0 + ty + 8 * i) * R + r0 + tx] = f2bf(tile[tx][ty + 8 * i]);
}

// ------- row LayerNorm (D=1024), f32 in -> bf16 out; optionally zero zbuf[row]
__global__ __launch_bounds__(256) void ln_rows(const float* __restrict__ x,
                                               const float* __restrict__ g,
                                               const float* __restrict__ bsh,
                                               u16* __restrict__ y,
                                               float* __restrict__ zbuf) {
  const size_t row = blockIdx.x;
  const int t = threadIdx.x;
  if (zbuf && t == 0) zbuf[row] = 0.f;
  float4 v = ((const float4*)(x + row * 1024))[t];
  float s = v.x + v.y + v.z + v.w;
  float q = v.x * v.x + v.y * v.y + v.z * v.z + v.w * v.w;
#pragma unroll
  for (int m = 1; m < 64; m <<= 1) { s += __shfl_xor(s, m); q += __shfl_xor(q, m); }
  __shared__ float sh[8];
  if ((t & 63) == 0) { sh[t >> 6] = s; sh[4 + (t >> 6)] = q; }
  __syncthreads();
  s = sh[0] + sh[1] + sh[2] + sh[3];
  q = sh[4] + sh[5] + sh[6] + sh[7];
  const float mu = s * (1.f / 1024.f);
  const float var = q * (1.f / 1024.f) - mu * mu;
  const float rs = rsqrtf(var + 1e-5f);
  const int c = t * 4;
  const float in[4] = {v.x, v.y, v.z, v.w};
  u16x4 o;
#pragma unroll
  for (int i = 0; i < 4; ++i) o[i] = f2bf((in[i] - mu) * rs * g[c + i] + bsh[c + i]);
  *(u16x4*)(y + row * 1024 + c) = o;
}

// ============ 256x256 MFMA GEMM, BK=32, 4-slot ring, 2-phase interleave ======
// C[M,N] = A[M,K] @ Bt[N,K]^T.  512 threads (8 waves = 2M x 4N), per-wave C
// block 128x64, acc[8][4] f32x4.  LDS ring: 4 slots x (A 16KB + B 16KB).
// Per K-tile, TWO phases in the verified m201 shape:
//  phA: {8 ds_read (a rows 0-63 + all b) | 2 gload_lds -> bar -> lgkm0 ->
//        SB0 -> prio1 -> 16 MFMA -> prio0 -> bar}
//  phB: {4 ds_read (a rows 64-127)       | 2 gload_lds -> bar -> lgkm0 ->
//        SB0 -> prio1 -> 16 MFMA -> prio0}  (loop-top vmcnt+bar closes it)
// Ring safety: stage slot (T+3)&3 holds tile T-1; every wave's T-1 phB
// lgkmcnt(0) precedes its top-of-T barrier arrival => all reads of that slot
// landed before any post-barrier stage write.  Staging UNCONDITIONAL with
// clamped tile index => 4 issues/tile/wave; at top of iter T issued = 12+4T,
// vmcnt(8) => completed >= 4T+4 => tile T resident; barrier -> collective.
// T2 k-slot XOR swizzle both-sides (LDS dest linear, global col pre-swizzled;
// read slot lane-constant kx) => conflict-free (verified: counter = 0).
// EPI 0: fused KV epilogue (col0<1024 -> K-path w/ rowssq+gain, else V-path)
// EPI 1: CK bf16 = gelu_exact(acc + biasK[col]), ldc = N.
template <int EPI>
__global__ __launch_bounds__(512, 2) void gemm256(
    const u16* __restrict__ A, const u16* __restrict__ Bt,
    const float* __restrict__ biasK, const float* __restrict__ biasV,
    const float* __restrict__ gcol, u16* __restrict__ CK, u16* __restrict__ CV,
    float* __restrict__ rowssq, int M, int N, int K, int RB, int CB) {
  __shared__ u16 lds[4][16384];  // per slot: A tile [256][32] then B tile [256][32]
  const int t = threadIdx.x;
  const int lane = t & 63;
  const int wave = t >> 6;
  const int wm = wave >> 2, wn = wave & 3;
  const int fr = lane & 15, kq = lane >> 4;

  // XCD-aware swizzle (gridDim.x % 8 == 0 for all our shapes)
  const int bid = blockIdx.x;
  const int cpx = gridDim.x >> 3;
  const int swz = (bid & 7) * cpx + (bid >> 3);
  const int rb = swz / CB, cb = swz % CB;  // cb-fastest
  const size_t row0 = (size_t)rb * 256, col0 = (size_t)cb * 256;

  f4v acc[8][4];
#pragma unroll
  for (int i = 0; i < 8; ++i)
#pragma unroll
    for (int n = 0; n < 4; ++n) acc[i][n] = (f4v){0.f, 0.f, 0.f, 0.f};

  // staging: thread t writes LDS linear (dest = half-base + t*16B); global
  // column pre-swizzled so slot s of row r holds k-block s^((r>>1)&3).
  const int srow = t >> 2;
  const int scol = (((t & 3) ^ ((t >> 3) & 3)) << 3);
  const u16* Ag0 = A + (row0 + srow) * (size_t)K + scol;
  const u16* Ag1 = Ag0 + (size_t)128 * K;
  const u16* Bg0 = Bt + (col0 + srow) * (size_t)K + scol;
  const u16* Bg1 = Bg0 + (size_t)128 * K;

  // read-side swizzled k-slot; rows are m*16+fr based so (row>>1)&3 == (fr>>1)&3
  const int kx = ((kq ^ ((fr >> 1) & 3)) << 3);

  const int NT = K >> 5;  // BK=32; requires NT >= 4 (K >= 128)

  // prologue: stage tiles 0..2 (12 loads; 4 per tile)
#pragma unroll
  for (int tt = 0; tt < 3; ++tt) {
    u16* sA = &lds[tt][0];
    u16* sB = &lds[tt][8192];
    gload16(Ag0 + tt * 32, sA + t * 8);
    gload16(Ag1 + tt * 32, sA + 4096 + t * 8);
    gload16(Bg0 + tt * 32, sB + t * 8);
    gload16(Bg1 + tt * 32, sB + 4096 + t * 8);
  }

#pragma unroll 4
  for (int T = 0; T < NT; ++T) {
    asm volatile("s_waitcnt vmcnt(8)" ::: "memory");
    __builtin_amdgcn_s_barrier();
    __builtin_amdgcn_sched_barrier(0);
    const u16* sA = &lds[T & 3][0];
    const u16* sB = &lds[T & 3][8192];
    const int Ts = (T + 3 < NT) ? T + 3 : NT - 1;  // clamp: uniform issue count
    u16* dA = &lds[(T + 3) & 3][0];
    u16* dB = &lds[(T + 3) & 3][8192];
    s8v a[4], b[4];
    // ---------------- phase A: M-frags 0-3 ----------------
#pragma unroll
    for (int m = 0; m < 4; ++m)
      a[m] = *(const s8v*)&sA[(wm * 128 + m * 16 + fr) * 32 + kx];
#pragma unroll
    for (int n = 0; n < 4; ++n)
      b[n] = *(const s8v*)&sB[(wn * 64 + n * 16 + fr) * 32 + kx];
    gload16(Ag0 + Ts * 32, dA + t * 8);
    gload16(Ag1 + Ts * 32, dA + 4096 + t * 8);
    __builtin_amdgcn_s_barrier();
    asm volatile("s_waitcnt lgkmcnt(0)" ::: "memory");
    __builtin_amdgcn_sched_barrier(0);
    __builtin_amdgcn_s_setprio(1);
#pragma unroll
    for (int m = 0; m < 4; ++m)
#pragma unroll
      for (int n = 0; n < 4; ++n)
        acc[m][n] = __builtin_amdgcn_mfma_f32_16x16x32_bf16(a[m], b[n], acc[m][n], 0, 0, 0);
    __builtin_amdgcn_s_setprio(0);
    __builtin_amdgcn_s_barrier();
    // ---------------- phase B: M-frags 4-7 (b held in regs) ----------------
#pragma unroll
    for (int m = 0; m < 4; ++m)
      a[m] = *(const s8v*)&sA[(wm * 128 + 64 + m * 16 + fr) * 32 + kx];
    gload16(Bg0 + Ts * 32, dB + t * 8);
    gload16(Bg1 + Ts * 32, dB + 4096 + t * 8);
    __builtin_amdgcn_s_barrier();
    asm volatile("s_waitcnt lgkmcnt(0)" ::: "memory");
    __builtin_amdgcn_sched_barrier(0);
    __builtin_amdgcn_s_setprio(1);
#pragma unroll
    for (int m = 0; m < 4; ++m)
#pragma unroll
      for (int n = 0; n < 4; ++n)
        acc[4 + m][n] = __builtin_amdgcn_mfma_f32_16x16x32_bf16(a[m], b[n], acc[4 + m][n], 0, 0, 0);
    __builtin_amdgcn_s_setprio(0);
  }

  // ---- epilogue ----
  const int kq4 = kq * 4;
  if (EPI == 0) {
    const bool isK = (col0 < 1024);
    if (isK) {
#pragma unroll
      for (int ai = 0; ai < 8; ++ai) {
        int cols[4];
        float bb[4], gg[4];
#pragma unroll
        for (int n = 0; n < 4; ++n) {
          cols[n] = (int)col0 + wn * 64 + n * 16 + fr;
          bb[n] = biasK[cols[n]];
          gg[n] = gcol[cols[n]];
        }
#pragma unroll
        for (int r = 0; r < 4; ++r) {
          const size_t grow = row0 + wm * 128 + ai * 16 + kq4 + r;
          float v[4];
#pragma unroll
          for (int n = 0; n < 4; ++n) v[n] = acc[ai][n][r] + bb[n];
          float s = v[0] * v[0] + v[1] * v[1] + v[2] * v[2] + v[3] * v[3];
          s += __shfl_xor(s, 1);
          s += __shfl_xor(s, 2);
          s += __shfl_xor(s, 4);
          s += __shfl_xor(s, 8);
          if (fr == 0) atomicAdd(&rowssq[grow], s);
#pragma unroll
          for (int n = 0; n < 4; ++n)
            CK[grow * 1024 + cols[n]] = f2bf(v[n] * gg[n]);
        }
      }
    } else {
#pragma unroll
      for (int ai = 0; ai < 8; ++ai) {
        int cols[4];
        float bb[4];
#pragma unroll
        for (int n = 0; n < 4; ++n) {
          cols[n] = (int)col0 - 1024 + wn * 64 + n * 16 + fr;
          bb[n] = biasV[cols[n]];
        }
#pragma unroll
        for (int r = 0; r < 4; ++r) {
          const size_t grow = row0 + wm * 128 + ai * 16 + kq4 + r;
#pragma unroll
          for (int n = 0; n < 4; ++n)
            CV[grow * 1024 + cols[n]] = f2bf(acc[ai][n][r] + bb[n]);
        }
      }
    }
  } else {
#pragma unroll
    for (int ai = 0; ai < 8; ++ai) {
      int cols[4];
      float bb[4];
#pragma unroll
      for (int n = 0; n < 4; ++n) {
        cols[n] = (int)col0 + wn * 64 + n * 16 + fr;
        bb[n] = biasK[cols[n]];
      }
#pragma unroll
      for (int r = 0; r < 4; ++r) {
        const size_t grow = row0 + wm * 128 + ai * 16 + kq4 + r;
#pragma unroll
        for (int n = 0; n < 4; ++n) {
          const float x = acc[ai][n][r] + bb[n];
          CK[grow * (size_t)N + cols[n]] = f2bf(0.5f * x * (1.f + erff(x * 0.70710678118654752f)));
        }
      }
    }
  }
}

// ---------------- 128x128 MFMA GEMM (m97 structure), epilogues ---------------
// Same T2 swizzle: linear LDS dest, pre-swizzled global col, lane-const kx.
// EPI 3: store f32 (acc+bias+extra[row,col])
// EPI 5: v=acc+bias; atomic rowssq += v^2; store bf16 v   (q-path)
// EPI 6: split-K partial: store f32 raw acc to Cv + z*M*N; K-range by blockIdx.z
template <int EPI>
__global__ __launch_bounds__(256) void gemm_bt(
    const u16* __restrict__ A, const u16* __restrict__ Bt,
    const float* __restrict__ bias, const float* __restrict__ gcol,
    void* __restrict__ Cv, const float* __restrict__ extra,
    float* __restrict__ rowssq, int M, int N, int K) {
  __shared__ u16 As[128 * 32];
  __shared__ u16 Bs[128 * 32];
  const int t = threadIdx.x;
  const int lane = t & 63;
  const int wave = t >> 6;
  const int wr = wave >> 1, wc = wave & 1;
  const size_t row0 = (size_t)blockIdx.y * 128;
  const size_t col0 = (size_t)blockIdx.x * 128;
  int Ksub = K, koff = 0;
  if (EPI == 6) { Ksub = K / gridDim.z; koff = blockIdx.z * Ksub; }

  f4v acc[4][4];
#pragma unroll
  for (int m = 0; m < 4; ++m)
#pragma unroll
    for (int n = 0; n < 4; ++n) acc[m][n] = (f4v){0.f, 0.f, 0.f, 0.f};

  const int sr = t >> 2;
  const int scw = (((t & 3) ^ ((t >> 3) & 3)) << 3);  // pre-swizzled global col
  const u16* Ag = A + (row0 + sr) * (size_t)K + koff + scw;
  const u16* Bg = Bt + (col0 + sr) * (size_t)K + koff + scw;
  u16* Al = &As[t * 8];  // linear dest
  u16* Bl = &Bs[t * 8];
  const int fr = lane & 15;
  const int kx = (((lane >> 4) ^ ((fr >> 1) & 3)) << 3);

  for (int k0 = 0; k0 < Ksub; k0 += 32) {
    gload16(Ag + k0, Al);
    gload16(Ag + k0 + (size_t)64 * K, Al + 64 * 32);
    gload16(Bg + k0, Bl);
    gload16(Bg + k0 + (size_t)64 * K, Bl + 64 * 32);
    __syncthreads();
    s8v a[4], b[4];
#pragma unroll
    for (int m = 0; m < 4; ++m)
      a[m] = *(const s8v*)&As[(wr * 64 + m * 16 + fr) * 32 + kx];
#pragma unroll
    for (int n = 0; n < 4; ++n)
      b[n] = *(const s8v*)&Bs[(wc * 64 + n * 16 + fr) * 32 + kx];
#pragma unroll
    for (int m = 0; m < 4; ++m)
#pragma unroll
      for (int n = 0; n < 4; ++n)
        acc[m][n] = __builtin_amdgcn_mfma_f32_16x16x32_bf16(a[m], b[n], acc[m][n], 0, 0, 0);
    __syncthreads();
  }

  float* Cp = (float*)Cv;
  if (EPI == 6) Cp += (size_t)blockIdx.z * M * (size_t)N;
  const int rg = (lane >> 4) * 4;
#pragma unroll
  for (int m = 0; m < 4; ++m) {
    int cols[4];
    float bvals[4];
#pragma unroll
    for (int n = 0; n < 4; ++n) {
      cols[n] = (int)col0 + wc * 64 + n * 16 + fr;
      bvals[n] = (EPI == 6) ? 0.f : bias[cols[n]];
    }
#pragma unroll
    for (int r = 0; r < 4; ++r) {
      const size_t grow = row0 + wr * 64 + m * 16 + rg + r;
      float v[4];
#pragma unroll
      for (int n = 0; n < 4; ++n) v[n] = acc[m][n][r] + bvals[n];
      if (EPI == 5) {
        float s = v[0] * v[0] + v[1] * v[1] + v[2] * v[2] + v[3] * v[3];
        s += __shfl_xor(s, 1);
        s += __shfl_xor(s, 2);
        s += __shfl_xor(s, 4);
        s += __shfl_xor(s, 8);
        if (fr == 0) atomicAdd(&rowssq[grow], s);
      }
#pragma unroll
      for (int n = 0; n < 4; ++n) {
        const size_t idx = grow * (size_t)N + cols[n];
        if (EPI == 3) {
          Cp[idx] = v[n] + extra[idx];
        } else if (EPI == 5) {
          ((u16*)Cv)[idx] = f2bf(v[n]);
        } else if (EPI == 6) {
          Cp[idx] = v[n];
        }
      }
    }
  }
}

// ---------------- attention with the faithful raw-reshape semantics ----------
// head h, key j in [0,32): kv position = 2h + j/16, d-slice = (j%16)*64 .. +64
// q applied here: q_eff[d] = qpre[d]*gq[d]*rsq_q*0.125 (rms of q folded)
__global__ __launch_bounds__(256) void attn_k(const u16* __restrict__ qf,
                                              const u16* __restrict__ kmat,
                                              const float* __restrict__ kssq,
                                              const u16* __restrict__ vmat,
                                              const float* __restrict__ gq,
                                              const float* __restrict__ qssq,
                                              u16* __restrict__ ao) {
  const int lb = blockIdx.x;
  const int t = threadIdx.x;
  const int wave = t >> 6, lane = t & 63;
  const int j = lane & 31, half = lane >> 5;
  const float rq = rsqrtf(qssq[lb] * (1.f / 1024.f) + 1e-6f) * 0.125f;
  __shared__ float po[64][17];
#pragma unroll
  for (int hi = 0; hi < 4; ++hi) {
    const int h = wave * 4 + hi;
    const int krow = lb * 32 + 2 * h + (j >> 4);
    const u16* kp = kmat + (size_t)krow * 1024 + (j & 15) * 64 + half * 32;
    const u16* qp = qf + (size_t)lb * 1024 + h * 64 + half * 32;
    const float* gqp = gq + h * 64 + half * 32;
    float s = 0.f;
#pragma unroll
    for (int cc = 0; cc < 4; ++cc) {
      s8v qv = *(const s8v*)(qp + cc * 8);
      s8v kv = *(const s8v*)(kp + cc * 8);
#pragma unroll
      for (int e = 0; e < 8; ++e)
        s += bf2f((u16)qv[e]) * gqp[cc * 8 + e] * bf2f((u16)kv[e]);
    }
    s += __shfl_xor(s, 32);
    s *= rsqrtf(kssq[krow] * (1.f / 1024.f) + 1e-6f) * rq;
    float mx = s;
#pragma unroll
    for (int m = 16; m >= 1; m >>= 1) mx = fmaxf(mx, __shfl_xor(mx, m));
    const float pe = __expf(s - mx);
    float sum = pe;
#pragma unroll
    for (int m = 16; m >= 1; m >>= 1) sum += __shfl_xor(sum, m);
    const float pr = pe / sum;
    float o = 0.f;
#pragma unroll
    for (int jj = 0; jj < 32; ++jj) {
      const int vrow = lb * 32 + 2 * h + (jj >> 4);
      const float vv = bf2f(vmat[(size_t)vrow * 1024 + (jj & 15) * 64 + lane]);
      o += __shfl(pr, jj) * vv;
    }
    po[lane][h] = o;  // hd = lane
  }
  __syncthreads();
  const int c = t * 4;
  u16x4 o4;
#pragma unroll
  for (int i = 0; i < 4; ++i) o4[i] = f2bf(po[(c + i) >> 4][(c + i) & 15]);
  *(u16x4*)(ao + (size_t)lb * 1024 + c) = o4;
}

// ------------- W2 split-K combine: out = p0 + p1 + b2[col] + resid -----------
__global__ __launch_bounds__(256) void combine_k(const float* __restrict__ p0,
                                                 const float* __restrict__ p1,
                                                 const float* __restrict__ b2,
                                                 const float* __restrict__ resid,
                                                 float* __restrict__ out) {
  const int i = blockIdx.x * 256 + threadIdx.x;  // float4 index
  float4 a = ((const float4*)p0)[i];
  float4 b = ((const float4*)p1)[i];
  float4 r = ((const float4*)resid)[i];
  float4 bb = ((const float4*)b2)[i & 255];
  float4 o;
  o.x = a.x + b.x + r.x + bb.x;
  o.y = a.y + b.y + r.y + bb.y;
  o.z = a.z + b.z + r.z + bb.z;
  o.w = a.w + b.w + r.w + bb.w;
  ((float4*)out)[i] = o;
}

// -----------------------------------------------------------------------------
extern "C" void kernel_launch(void* const* d_in, const int* in_sizes, int n_in,
                              void* d_out, int out_size, void* d_ws, size_t ws_size,
                              hipStream_t stream) {
  const float* query  = (const float*)d_in[0];
  const float* pf     = (const float*)d_in[1];
  const float* lnq_g  = (const float*)d_in[2];
  const float* lnq_b  = (const float*)d_in[3];
  const float* lnkv_g = (const float*)d_in[4];
  const float* lnkv_b = (const float*)d_in[5];
  const float* Wq     = (const float*)d_in[6];
  const float* bq     = (const float*)d_in[7];
  const float* Wk     = (const float*)d_in[8];
  const float* bk     = (const float*)d_in[9];
  const float* Wv     = (const float*)d_in[10];
  const float* bv     = (const float*)d_in[11];
  const float* rmsq_g = (const float*)d_in[12];
  const float* rmsk_g = (const float*)d_in[13];
  const float* Wo     = (const float*)d_in[14];
  const float* bo     = (const float*)d_in[15];
  const float* mlpn_g = (const float*)d_in[16];
  const float* mlpn_b = (const float*)d_in[17];
  const float* W1     = (const float*)d_in[18];
  const float* b1     = (const float*)d_in[19];
  const float* W2     = (const float*)d_in[20];
  const float* b2     = (const float*)d_in[21];
  float* out = (float*)d_out;

  char* p = (char*)d_ws;
  auto alloc = [&](size_t n) {
    char* r = p;
    p += (n + 255) & ~(size_t)255;
    return r;
  };

  u16* Wqt = (u16*)alloc((size_t)1024 * 1024 * 2);
  u16* KVt = (u16*)alloc((size_t)2048 * 1024 * 2);  // [Wk^T ; Wv^T]
  u16* Wot = (u16*)alloc((size_t)1024 * 1024 * 2);
  u16* W1t = (u16*)alloc((size_t)1024 * 4096 * 2);
  u16* W2t = (u16*)alloc((size_t)4096 * 1024 * 2);
  u16* qln = (u16*)alloc((size_t)4096 * 1024 * 2);
  u16* qpre = (u16*)alloc((size_t)4096 * 1024 * 2);
  float* qssq = (float*)alloc((size_t)4096 * 4);
  u16* attn_o = (u16*)alloc((size_t)4096 * 1024 * 2);
  float* outbuf = (float*)alloc((size_t)4096 * 1024 * 4);
  u16* hbuf = (u16*)alloc((size_t)4096 * 1024 * 2);
  u16* mid = (u16*)alloc((size_t)4096 * 4096 * 2);
  float* w2p = (float*)alloc((size_t)2 * 4096 * 1024 * 4);  // split-K partials
  const size_t ROWS = 131072;
  u16* kvln = (u16*)alloc(ROWS * 2048);
  u16* kmat = (u16*)alloc(ROWS * 2048);
  u16* vmat = (u16*)alloc(ROWS * 2048);
  float* kssq = (float*)alloc(ROWS * 4);

  // weight transpose+convert: W[K][N] f32 -> Wt[N][K] bf16
  transpose_w<<<dim3(32, 32), 256, 0, stream>>>(Wq, Wqt, 1024, 1024);
  transpose_w<<<dim3(32, 32), 256, 0, stream>>>(Wk, KVt, 1024, 1024);
  transpose_w<<<dim3(32, 32), 256, 0, stream>>>(Wv, KVt + (size_t)1024 * 1024, 1024, 1024);
  transpose_w<<<dim3(32, 32), 256, 0, stream>>>(Wo, Wot, 1024, 1024);
  transpose_w<<<dim3(128, 32), 256, 0, stream>>>(W1, W1t, 1024, 4096);
  transpose_w<<<dim3(32, 128), 256, 0, stream>>>(W2, W2t, 4096, 1024);

  // q path: LN -> GEMM(Wq)+bq (epilogue: bf16 qpre + qssq atomics)
  ln_rows<<<4096, 256, 0, stream>>>(query, lnq_g, lnq_b, qln, qssq);
  gemm_bt<5><<<dim3(8, 32), 256, 0, stream>>>(qln, Wqt, bq, nullptr, qpre, nullptr,
                                              qssq, 4096, 1024, 1024);

  // kv path: full-size LN, single fused K+V GEMM, single attn
  ln_rows<<<(unsigned)ROWS, 256, 0, stream>>>(pf, lnkv_g, lnkv_b, kvln, kssq);
  gemm256<0><<<512 * 8, 512, 0, stream>>>(kvln, KVt, bk, bv, rmsk_g, kmat, vmat,
                                          kssq, (int)ROWS, 2048, 1024, 512, 8);
  attn_k<<<4096, 256, 0, stream>>>(qpre, kmat, kssq, vmat, rmsq_g, qssq, attn_o);

  // out = attn_o @ Wo + bo + query  (f32)
  gemm_bt<3><<<dim3(8, 32), 256, 0, stream>>>(attn_o, Wot, bo, nullptr, outbuf, query,
                                              nullptr, 4096, 1024, 1024);
  // h = LN(out)
  ln_rows<<<4096, 256, 0, stream>>>(outbuf, mlpn_g, mlpn_b, hbuf, nullptr);
  // mid = gelu(h @ W1 + b1)  -- 256^2 kernel, grid 16x16
  gemm256<1><<<16 * 16, 512, 0, stream>>>(hbuf, W1t, b1, nullptr, nullptr, mid, nullptr,
                                          nullptr, 4096, 4096, 1024, 16, 16);
  // final = mid @ W2 (split-K=2 partials) + b2 + out
  gemm_bt<6><<<dim3(8, 32, 2), 256, 0, stream>>>(mid, W2t, nullptr, nullptr, w2p,
                                                 nullptr, nullptr, 4096, 1024, 4096);
  combine_k<<<4096, 256, 0, stream>>>(w2p, w2p + (size_t)4096 * 1024, b2, outbuf, out);
}

// Round 6
// 1079.074 us; speedup vs baseline: 1.0221x; 1.0125x over previous
//
#include <hip/hip_runtime.h>
#include <stdint.h>

#define DEVI __device__ __forceinline__

typedef unsigned short u16;
typedef short s8v __attribute__((ext_vector_type(8)));
typedef float f4v __attribute__((ext_vector_type(4)));
typedef u16 u16x4 __attribute__((ext_vector_type(4)));

DEVI u16 f2bf(float f) {
  unsigned u = __float_as_uint(f);
  u += 0x7fffu + ((u >> 16) & 1u);
  return (u16)(u >> 16);
}
DEVI float bf2f(u16 h) { return __uint_as_float(((unsigned)h) << 16); }

DEVI void gload16(const void* g, void* l) {
  __builtin_amdgcn_global_load_lds(
      (const __attribute__((address_space(1))) void*)(uintptr_t)g,
      (__attribute__((address_space(3))) void*)(uintptr_t)l, 16, 0, 0);
}

// ---------------- transpose + f32->bf16 convert: W[R][C] -> Wt[C][R] ----------
__global__ __launch_bounds__(256) void transpose_w(const float* __restrict__ W,
                                                   u16* __restrict__ Wt, int R, int C) {
  __shared__ float tile[32][33];
  const int tx = threadIdx.x & 31, ty = threadIdx.x >> 5;
  const int r0 = blockIdx.y * 32, c0 = blockIdx.x * 32;
#pragma unroll
  for (int i = 0; i < 4; ++i)
    tile[ty + 8 * i][tx] = W[(size_t)(r0 + ty + 8 * i) * C + c0 + tx];
  __syncthreads();
#pragma unroll
  for (int i = 0; i < 4; ++i)
    Wt[(size_t)(c0 + ty + 8 * i) * R + r0 + tx] = f2bf(tile[tx][ty + 8 * i]);
}

// ------- row LayerNorm (D=1024), f32 in -> bf16 out; optionally zero zbuf[row]
__global__ __launch_bounds__(256) void ln_rows(const float* __restrict__ x,
                                               const float* __restrict__ g,
                                               const float* __restrict__ bsh,
                                               u16* __restrict__ y,
                                               float* __restrict__ zbuf) {
  const size_t row = blockIdx.x;
  const int t = threadIdx.x;
  if (zbuf && t == 0) zbuf[row] = 0.f;
  float4 v = ((const float4*)(x + row * 1024))[t];
  float s = v.x + v.y + v.z + v.w;
  float q = v.x * v.x + v.y * v.y + v.z * v.z + v.w * v.w;
#pragma unroll
  for (int m = 1; m < 64; m <<= 1) { s += __shfl_xor(s, m); q += __shfl_xor(q, m); }
  __shared__ float sh[8];
  if ((t & 63) == 0) { sh[t >> 6] = s; sh[4 + (t >> 6)] = q; }
  __syncthreads();
  s = sh[0] + sh[1] + sh[2] + sh[3];
  q = sh[4] + sh[5] + sh[6] + sh[7];
  const float mu = s * (1.f / 1024.f);
  const float var = q * (1.f / 1024.f) - mu * mu;
  const float rs = rsqrtf(var + 1e-5f);
  const int c = t * 4;
  const float in[4] = {v.x, v.y, v.z, v.w};
  u16x4 o;
#pragma unroll
  for (int i = 0; i < 4; ++i) o[i] = f2bf((in[i] - mu) * rs * g[c + i] + bsh[c + i]);
  *(u16x4*)(y + row * 1024 + c) = o;
}

// ============ 256x256 MFMA GEMM, BK=32, 4-slot ring, 2-phase interleave ======
// (structure unchanged from R5; verified 0 bank conflicts, ring invariants in
// comments of prior revs).  A expected L3-resident via chunked pipeline.
template <int EPI>
__global__ __launch_bounds__(512, 2) void gemm256(
    const u16* __restrict__ A, const u16* __restrict__ Bt,
    const float* __restrict__ biasK, const float* __restrict__ biasV,
    const float* __restrict__ gcol, u16* __restrict__ CK, u16* __restrict__ CV,
    float* __restrict__ rowssq, int M, int N, int K, int RB, int CB) {
  __shared__ u16 lds[4][16384];  // per slot: A tile [256][32] then B tile [256][32]
  const int t = threadIdx.x;
  const int lane = t & 63;
  const int wave = t >> 6;
  const int wm = wave >> 2, wn = wave & 3;
  const int fr = lane & 15, kq = lane >> 4;

  const int bid = blockIdx.x;
  const int cpx = gridDim.x >> 3;
  const int swz = (bid & 7) * cpx + (bid >> 3);
  const int rb = swz / CB, cb = swz % CB;  // cb-fastest
  const size_t row0 = (size_t)rb * 256, col0 = (size_t)cb * 256;

  f4v acc[8][4];
#pragma unroll
  for (int i = 0; i < 8; ++i)
#pragma unroll
    for (int n = 0; n < 4; ++n) acc[i][n] = (f4v){0.f, 0.f, 0.f, 0.f};

  const int srow = t >> 2;
  const int scol = (((t & 3) ^ ((t >> 3) & 3)) << 3);
  const u16* Ag0 = A + (row0 + srow) * (size_t)K + scol;
  const u16* Ag1 = Ag0 + (size_t)128 * K;
  const u16* Bg0 = Bt + (col0 + srow) * (size_t)K + scol;
  const u16* Bg1 = Bg0 + (size_t)128 * K;

  const int kx = ((kq ^ ((fr >> 1) & 3)) << 3);

  const int NT = K >> 5;

#pragma unroll
  for (int tt = 0; tt < 3; ++tt) {
    u16* sA = &lds[tt][0];
    u16* sB = &lds[tt][8192];
    gload16(Ag0 + tt * 32, sA + t * 8);
    gload16(Ag1 + tt * 32, sA + 4096 + t * 8);
    gload16(Bg0 + tt * 32, sB + t * 8);
    gload16(Bg1 + tt * 32, sB + 4096 + t * 8);
  }

#pragma unroll 4
  for (int T = 0; T < NT; ++T) {
    asm volatile("s_waitcnt vmcnt(8)" ::: "memory");
    __builtin_amdgcn_s_barrier();
    __builtin_amdgcn_sched_barrier(0);
    const u16* sA = &lds[T & 3][0];
    const u16* sB = &lds[T & 3][8192];
    const int Ts = (T + 3 < NT) ? T + 3 : NT - 1;  // clamp: uniform issue count
    u16* dA = &lds[(T + 3) & 3][0];
    u16* dB = &lds[(T + 3) & 3][8192];
    s8v a[4], b[4];
    // ---------------- phase A: M-frags 0-3 ----------------
#pragma unroll
    for (int m = 0; m < 4; ++m)
      a[m] = *(const s8v*)&sA[(wm * 128 + m * 16 + fr) * 32 + kx];
#pragma unroll
    for (int n = 0; n < 4; ++n)
      b[n] = *(const s8v*)&sB[(wn * 64 + n * 16 + fr) * 32 + kx];
    gload16(Ag0 + Ts * 32, dA + t * 8);
    gload16(Ag1 + Ts * 32, dA + 4096 + t * 8);
    __builtin_amdgcn_s_barrier();
    asm volatile("s_waitcnt lgkmcnt(0)" ::: "memory");
    __builtin_amdgcn_sched_barrier(0);
    __builtin_amdgcn_s_setprio(1);
#pragma unroll
    for (int m = 0; m < 4; ++m)
#pragma unroll
      for (int n = 0; n < 4; ++n)
        acc[m][n] = __builtin_amdgcn_mfma_f32_16x16x32_bf16(a[m], b[n], acc[m][n], 0, 0, 0);
    __builtin_amdgcn_s_setprio(0);
    __builtin_amdgcn_s_barrier();
    // ---------------- phase B: M-frags 4-7 (b held in regs) ----------------
#pragma unroll
    for (int m = 0; m < 4; ++m)
      a[m] = *(const s8v*)&sA[(wm * 128 + 64 + m * 16 + fr) * 32 + kx];
    gload16(Bg0 + Ts * 32, dB + t * 8);
    gload16(Bg1 + Ts * 32, dB + 4096 + t * 8);
    __builtin_amdgcn_s_barrier();
    asm volatile("s_waitcnt lgkmcnt(0)" ::: "memory");
    __builtin_amdgcn_sched_barrier(0);
    __builtin_amdgcn_s_setprio(1);
#pragma unroll
    for (int m = 0; m < 4; ++m)
#pragma unroll
      for (int n = 0; n < 4; ++n)
        acc[4 + m][n] = __builtin_amdgcn_mfma_f32_16x16x32_bf16(a[m], b[n], acc[4 + m][n], 0, 0, 0);
    __builtin_amdgcn_s_setprio(0);
  }

  // ---- epilogue ----
  const int kq4 = kq * 4;
  if (EPI == 0) {
    const bool isK = (col0 < 1024);
    if (isK) {
#pragma unroll
      for (int ai = 0; ai < 8; ++ai) {
        int cols[4];
        float bb[4], gg[4];
#pragma unroll
        for (int n = 0; n < 4; ++n) {
          cols[n] = (int)col0 + wn * 64 + n * 16 + fr;
          bb[n] = biasK[cols[n]];
          gg[n] = gcol[cols[n]];
        }
#pragma unroll
        for (int r = 0; r < 4; ++r) {
          const size_t grow = row0 + wm * 128 + ai * 16 + kq4 + r;
          float v[4];
#pragma unroll
          for (int n = 0; n < 4; ++n) v[n] = acc[ai][n][r] + bb[n];
          float s = v[0] * v[0] + v[1] * v[1] + v[2] * v[2] + v[3] * v[3];
          s += __shfl_xor(s, 1);
          s += __shfl_xor(s, 2);
          s += __shfl_xor(s, 4);
          s += __shfl_xor(s, 8);
          if (fr == 0) atomicAdd(&rowssq[grow], s);
#pragma unroll
          for (int n = 0; n < 4; ++n)
            CK[grow * 1024 + cols[n]] = f2bf(v[n] * gg[n]);
        }
      }
    } else {
#pragma unroll
      for (int ai = 0; ai < 8; ++ai) {
        int cols[4];
        float bb[4];
#pragma unroll
        for (int n = 0; n < 4; ++n) {
          cols[n] = (int)col0 - 1024 + wn * 64 + n * 16 + fr;
          bb[n] = biasV[cols[n]];
        }
#pragma unroll
        for (int r = 0; r < 4; ++r) {
          const size_t grow = row0 + wm * 128 + ai * 16 + kq4 + r;
#pragma unroll
          for (int n = 0; n < 4; ++n)
            CV[grow * 1024 + cols[n]] = f2bf(acc[ai][n][r] + bb[n]);
        }
      }
    }
  } else {
#pragma unroll
    for (int ai = 0; ai < 8; ++ai) {
      int cols[4];
      float bb[4];
#pragma unroll
      for (int n = 0; n < 4; ++n) {
        cols[n] = (int)col0 + wn * 64 + n * 16 + fr;
        bb[n] = biasK[cols[n]];
      }
#pragma unroll
      for (int r = 0; r < 4; ++r) {
        const size_t grow = row0 + wm * 128 + ai * 16 + kq4 + r;
#pragma unroll
        for (int n = 0; n < 4; ++n) {
          const float x = acc[ai][n][r] + bb[n];
          CK[grow * (size_t)N + cols[n]] = f2bf(0.5f * x * (1.f + erff(x * 0.70710678118654752f)));
        }
      }
    }
  }
}

// ---------------- 128x128 MFMA GEMM (m97 structure), epilogues ---------------
// EPI 3: store f32 (acc+bias+extra[row,col])
// EPI 5: v=acc+bias; atomic rowssq += v^2; store bf16 v   (q-path)
// EPI 6: split-K partial: store f32 raw acc to Cv + z*M*N; K-range by blockIdx.z
template <int EPI>
__global__ __launch_bounds__(256) void gemm_bt(
    const u16* __restrict__ A, const u16* __restrict__ Bt,
    const float* __restrict__ bias, const float* __restrict__ gcol,
    void* __restrict__ Cv, const float* __restrict__ extra,
    float* __restrict__ rowssq, int M, int N, int K) {
  __shared__ u16 As[128 * 32];
  __shared__ u16 Bs[128 * 32];
  const int t = threadIdx.x;
  const int lane = t & 63;
  const int wave = t >> 6;
  const int wr = wave >> 1, wc = wave & 1;
  const size_t row0 = (size_t)blockIdx.y * 128;
  const size_t col0 = (size_t)blockIdx.x * 128;
  int Ksub = K, koff = 0;
  if (EPI == 6) { Ksub = K / gridDim.z; koff = blockIdx.z * Ksub; }

  f4v acc[4][4];
#pragma unroll
  for (int m = 0; m < 4; ++m)
#pragma unroll
    for (int n = 0; n < 4; ++n) acc[m][n] = (f4v){0.f, 0.f, 0.f, 0.f};

  const int sr = t >> 2;
  const int scw = (((t & 3) ^ ((t >> 3) & 3)) << 3);  // pre-swizzled global col
  const u16* Ag = A + (row0 + sr) * (size_t)K + koff + scw;
  const u16* Bg = Bt + (col0 + sr) * (size_t)K + koff + scw;
  u16* Al = &As[t * 8];  // linear dest
  u16* Bl = &Bs[t * 8];
  const int fr = lane & 15;
  const int kx = (((lane >> 4) ^ ((fr >> 1) & 3)) << 3);

  for (int k0 = 0; k0 < Ksub; k0 += 32) {
    gload16(Ag + k0, Al);
    gload16(Ag + k0 + (size_t)64 * K, Al + 64 * 32);
    gload16(Bg + k0, Bl);
    gload16(Bg + k0 + (size_t)64 * K, Bl + 64 * 32);
    __syncthreads();
    s8v a[4], b[4];
#pragma unroll
    for (int m = 0; m < 4; ++m)
      a[m] = *(const s8v*)&As[(wr * 64 + m * 16 + fr) * 32 + kx];
#pragma unroll
    for (int n = 0; n < 4; ++n)
      b[n] = *(const s8v*)&Bs[(wc * 64 + n * 16 + fr) * 32 + kx];
#pragma unroll
    for (int m = 0; m < 4; ++m)
#pragma unroll
      for (int n = 0; n < 4; ++n)
        acc[m][n] = __builtin_amdgcn_mfma_f32_16x16x32_bf16(a[m], b[n], acc[m][n], 0, 0, 0);
    __syncthreads();
  }

  float* Cp = (float*)Cv;
  if (EPI == 6) Cp += (size_t)blockIdx.z * M * (size_t)N;
  const int rg = (lane >> 4) * 4;
#pragma unroll
  for (int m = 0; m < 4; ++m) {
    int cols[4];
    float bvals[4];
#pragma unroll
    for (int n = 0; n < 4; ++n) {
      cols[n] = (int)col0 + wc * 64 + n * 16 + fr;
      bvals[n] = (EPI == 6) ? 0.f : bias[cols[n]];
    }
#pragma unroll
    for (int r = 0; r < 4; ++r) {
      const size_t grow = row0 + wr * 64 + m * 16 + rg + r;
      float v[4];
#pragma unroll
      for (int n = 0; n < 4; ++n) v[n] = acc[m][n][r] + bvals[n];
      if (EPI == 5) {
        float s = v[0] * v[0] + v[1] * v[1] + v[2] * v[2] + v[3] * v[3];
        s += __shfl_xor(s, 1);
        s += __shfl_xor(s, 2);
        s += __shfl_xor(s, 4);
        s += __shfl_xor(s, 8);
        if (fr == 0) atomicAdd(&rowssq[grow], s);
      }
#pragma unroll
      for (int n = 0; n < 4; ++n) {
        const size_t idx = grow * (size_t)N + cols[n];
        if (EPI == 3) {
          Cp[idx] = v[n] + extra[idx];
        } else if (EPI == 5) {
          ((u16*)Cv)[idx] = f2bf(v[n]);
        } else if (EPI == 6) {
          Cp[idx] = v[n];
        }
      }
    }
  }
}

// ---------------- attention with the faithful raw-reshape semantics ----------
// head h, key j in [0,32): kv position = 2h + j/16, d-slice = (j%16)*64 .. +64
// q applied here: q_eff[d] = qpre[d]*gq[d]*rsq_q*0.125 (rms of q folded)
__global__ __launch_bounds__(256) void attn_k(const u16* __restrict__ qf,
                                              const u16* __restrict__ kmat,
                                              const float* __restrict__ kssq,
                                              const u16* __restrict__ vmat,
                                              const float* __restrict__ gq,
                                              const float* __restrict__ qssq,
                                              u16* __restrict__ ao) {
  const int lb = blockIdx.x;
  const int t = threadIdx.x;
  const int wave = t >> 6, lane = t & 63;
  const int j = lane & 31, half = lane >> 5;
  const float rq = rsqrtf(qssq[lb] * (1.f / 1024.f) + 1e-6f) * 0.125f;
  __shared__ float po[64][17];
#pragma unroll
  for (int hi = 0; hi < 4; ++hi) {
    const int h = wave * 4 + hi;
    const int krow = lb * 32 + 2 * h + (j >> 4);
    const u16* kp = kmat + (size_t)krow * 1024 + (j & 15) * 64 + half * 32;
    const u16* qp = qf + (size_t)lb * 1024 + h * 64 + half * 32;
    const float* gqp = gq + h * 64 + half * 32;
    float s = 0.f;
#pragma unroll
    for (int cc = 0; cc < 4; ++cc) {
      s8v qv = *(const s8v*)(qp + cc * 8);
      s8v kv = *(const s8v*)(kp + cc * 8);
#pragma unroll
      for (int e = 0; e < 8; ++e)
        s += bf2f((u16)qv[e]) * gqp[cc * 8 + e] * bf2f((u16)kv[e]);
    }
    s += __shfl_xor(s, 32);
    s *= rsqrtf(kssq[krow] * (1.f / 1024.f) + 1e-6f) * rq;
    float mx = s;
#pragma unroll
    for (int m = 16; m >= 1; m >>= 1) mx = fmaxf(mx, __shfl_xor(mx, m));
    const float pe = __expf(s - mx);
    float sum = pe;
#pragma unroll
    for (int m = 16; m >= 1; m >>= 1) sum += __shfl_xor(sum, m);
    const float pr = pe / sum;
    float o = 0.f;
#pragma unroll
    for (int jj = 0; jj < 32; ++jj) {
      const int vrow = lb * 32 + 2 * h + (jj >> 4);
      const float vv = bf2f(vmat[(size_t)vrow * 1024 + (jj & 15) * 64 + lane]);
      o += __shfl(pr, jj) * vv;
    }
    po[lane][h] = o;  // hd = lane
  }
  __syncthreads();
  const int c = t * 4;
  u16x4 o4;
#pragma unroll
  for (int i = 0; i < 4; ++i) o4[i] = f2bf(po[(c + i) >> 4][(c + i) & 15]);
  *(u16x4*)(ao + (size_t)lb * 1024 + c) = o4;
}

// ------------- W2 split-K combine: out = p0 + p1 + b2[col] + resid -----------
__global__ __launch_bounds__(256) void combine_k(const float* __restrict__ p0,
                                                 const float* __restrict__ p1,
                                                 const float* __restrict__ b2,
                                                 const float* __restrict__ resid,
                                                 float* __restrict__ out) {
  const int i = blockIdx.x * 256 + threadIdx.x;  // float4 index
  float4 a = ((const float4*)p0)[i];
  float4 b = ((const float4*)p1)[i];
  float4 r = ((const float4*)resid)[i];
  float4 bb = ((const float4*)b2)[i & 255];
  float4 o;
  o.x = a.x + b.x + r.x + bb.x;
  o.y = a.y + b.y + r.y + bb.y;
  o.z = a.z + b.z + r.z + bb.z;
  o.w = a.w + b.w + r.w + bb.w;
  ((float4*)out)[i] = o;
}

// -----------------------------------------------------------------------------
extern "C" void kernel_launch(void* const* d_in, const int* in_sizes, int n_in,
                              void* d_out, int out_size, void* d_ws, size_t ws_size,
                              hipStream_t stream) {
  const float* query  = (const float*)d_in[0];
  const float* pf     = (const float*)d_in[1];
  const float* lnq_g  = (const float*)d_in[2];
  const float* lnq_b  = (const float*)d_in[3];
  const float* lnkv_g = (const float*)d_in[4];
  const float* lnkv_b = (const float*)d_in[5];
  const float* Wq     = (const float*)d_in[6];
  const float* bq     = (const float*)d_in[7];
  const float* Wk     = (const float*)d_in[8];
  const float* bk     = (const float*)d_in[9];
  const float* Wv     = (const float*)d_in[10];
  const float* bv     = (const float*)d_in[11];
  const float* rmsq_g = (const float*)d_in[12];
  const float* rmsk_g = (const float*)d_in[13];
  const float* Wo     = (const float*)d_in[14];
  const float* bo     = (const float*)d_in[15];
  const float* mlpn_g = (const float*)d_in[16];
  const float* mlpn_b = (const float*)d_in[17];
  const float* W1     = (const float*)d_in[18];
  const float* b1     = (const float*)d_in[19];
  const float* W2     = (const float*)d_in[20];
  const float* b2     = (const float*)d_in[21];
  float* out = (float*)d_out;

  char* p = (char*)d_ws;
  auto alloc = [&](size_t n) {
    char* r = p;
    p += (n + 255) & ~(size_t)255;
    return r;
  };

  u16* Wqt = (u16*)alloc((size_t)1024 * 1024 * 2);
  u16* KVt = (u16*)alloc((size_t)2048 * 1024 * 2);  // [Wk^T ; Wv^T]
  u16* Wot = (u16*)alloc((size_t)1024 * 1024 * 2);
  u16* W1t = (u16*)alloc((size_t)1024 * 4096 * 2);
  u16* W2t = (u16*)alloc((size_t)4096 * 1024 * 2);
  u16* qln = (u16*)alloc((size_t)4096 * 1024 * 2);
  u16* qpre = (u16*)alloc((size_t)4096 * 1024 * 2);
  float* qssq = (float*)alloc((size_t)4096 * 4);
  u16* attn_o = (u16*)alloc((size_t)4096 * 1024 * 2);
  float* outbuf = (float*)alloc((size_t)4096 * 1024 * 4);
  u16* hbuf = (u16*)alloc((size_t)4096 * 1024 * 2);
  u16* mid = (u16*)alloc((size_t)4096 * 4096 * 2);
  float* w2p = (float*)alloc((size_t)2 * 4096 * 1024 * 4);  // split-K partials

  // chunked KV pipeline buffers (NC chunks; chunk data stays L3-resident)
  const size_t used = (size_t)(p - (char*)d_ws);
  int NC = 4;
  while (NC < 64) {
    size_t rows_try = (size_t)131072 / NC;
    if (used + 3 * (rows_try * 2048 + 256) + rows_try * 4 + 256 <= ws_size) break;
    NC *= 2;
  }
  const size_t rows = (size_t)131072 / NC;
  u16* kvln = (u16*)alloc(rows * 2048);
  u16* kmat = (u16*)alloc(rows * 2048);
  u16* vmat = (u16*)alloc(rows * 2048);
  float* kssq = (float*)alloc(rows * 4);

  // weight transpose+convert: W[K][N] f32 -> Wt[N][K] bf16
  transpose_w<<<dim3(32, 32), 256, 0, stream>>>(Wq, Wqt, 1024, 1024);
  transpose_w<<<dim3(32, 32), 256, 0, stream>>>(Wk, KVt, 1024, 1024);
  transpose_w<<<dim3(32, 32), 256, 0, stream>>>(Wv, KVt + (size_t)1024 * 1024, 1024, 1024);
  transpose_w<<<dim3(32, 32), 256, 0, stream>>>(Wo, Wot, 1024, 1024);
  transpose_w<<<dim3(128, 32), 256, 0, stream>>>(W1, W1t, 1024, 4096);
  transpose_w<<<dim3(32, 128), 256, 0, stream>>>(W2, W2t, 4096, 1024);

  // q path: LN -> GEMM(Wq)+bq (epilogue: bf16 qpre + qssq atomics)
  ln_rows<<<4096, 256, 0, stream>>>(query, lnq_g, lnq_b, qln, qssq);
  gemm_bt<5><<<dim3(8, 32), 256, 0, stream>>>(qln, Wqt, bq, nullptr, qpre, nullptr,
                                              qssq, 4096, 1024, 1024);

  // kv path: chunked ln -> fused K+V gemm256 -> attn (chunk stays in L3)
  const int bpc = 4096 / NC;
  const int RB = (int)(rows / 256);
  for (int c = 0; c < NC; ++c) {
    ln_rows<<<(unsigned)rows, 256, 0, stream>>>(pf + (size_t)c * rows * 1024, lnkv_g,
                                                lnkv_b, kvln, kssq);
    gemm256<0><<<RB * 8, 512, 0, stream>>>(kvln, KVt, bk, bv, rmsk_g, kmat, vmat,
                                           kssq, (int)rows, 2048, 1024, RB, 8);
    attn_k<<<bpc, 256, 0, stream>>>(qpre + (size_t)c * bpc * 1024, kmat, kssq, vmat,
                                    rmsq_g, qssq + (size_t)c * bpc,
                                    attn_o + (size_t)c * bpc * 1024);
  }

  // out = attn_o @ Wo + bo + query  (f32)
  gemm_bt<3><<<dim3(8, 32), 256, 0, stream>>>(attn_o, Wot, bo, nullptr, outbuf, query,
                                              nullptr, 4096, 1024, 1024);
  // h = LN(out)
  ln_rows<<<4096, 256, 0, stream>>>(outbuf, mlpn_g, mlpn_b, hbuf, nullptr);
  // mid = gelu(h @ W1 + b1)  -- 256^2 kernel, grid 16x16
  gemm256<1><<<16 * 16, 512, 0, stream>>>(hbuf, W1t, b1, nullptr, nullptr, mid, nullptr,
                                          nullptr, 4096, 4096, 1024, 16, 16);
  // final = mid @ W2 (split-K=2 partials) + b2 + out
  gemm_bt<6><<<dim3(8, 32, 2), 256, 0, stream>>>(mid, W2t, nullptr, nullptr, w2p,
                                                 nullptr, nullptr, 4096, 1024, 4096);
  combine_k<<<4096, 256, 0, stream>>>(w2p, w2p + (size_t)4096 * 1024, b2, outbuf, out);
}

// Round 7
// 1070.290 us; speedup vs baseline: 1.0305x; 1.0082x over previous
//
#include <hip/hip_runtime.h>
#include <stdint.h>

#define DEVI __device__ __forceinline__

typedef unsigned short u16;
typedef short s8v __attribute__((ext_vector_type(8)));
typedef float f4v __attribute__((ext_vector_type(4)));
typedef u16 u16x4 __attribute__((ext_vector_type(4)));

DEVI u16 f2bf(float f) {
  unsigned u = __float_as_uint(f);
  u += 0x7fffu + ((u >> 16) & 1u);
  return (u16)(u >> 16);
}
DEVI float bf2f(u16 h) { return __uint_as_float(((unsigned)h) << 16); }

DEVI void gload16(const void* g, void* l) {
  __builtin_amdgcn_global_load_lds(
      (const __attribute__((address_space(1))) void*)(uintptr_t)g,
      (__attribute__((address_space(3))) void*)(uintptr_t)l, 16, 0, 0);
}

// ---------------- transpose + f32->bf16 convert: W[R][C] -> Wt[C][R] ----------
__global__ __launch_bounds__(256) void transpose_w(const float* __restrict__ W,
                                                   u16* __restrict__ Wt, int R, int C) {
  __shared__ float tile[32][33];
  const int tx = threadIdx.x & 31, ty = threadIdx.x >> 5;
  const int r0 = blockIdx.y * 32, c0 = blockIdx.x * 32;
#pragma unroll
  for (int i = 0; i < 4; ++i)
    tile[ty + 8 * i][tx] = W[(size_t)(r0 + ty + 8 * i) * C + c0 + tx];
  __syncthreads();
#pragma unroll
  for (int i = 0; i < 4; ++i)
    Wt[(size_t)(c0 + ty + 8 * i) * R + r0 + tx] = f2bf(tile[tx][ty + 8 * i]);
}

// ------- row LayerNorm (D=1024), f32 in -> bf16 out; optionally zero zbuf[row]
__global__ __launch_bounds__(256) void ln_rows(const float* __restrict__ x,
                                               const float* __restrict__ g,
                                               const float* __restrict__ bsh,
                                               u16* __restrict__ y,
                                               float* __restrict__ zbuf) {
  const size_t row = blockIdx.x;
  const int t = threadIdx.x;
  if (zbuf && t == 0) zbuf[row] = 0.f;
  float4 v = ((const float4*)(x + row * 1024))[t];
  float s = v.x + v.y + v.z + v.w;
  float q = v.x * v.x + v.y * v.y + v.z * v.z + v.w * v.w;
#pragma unroll
  for (int m = 1; m < 64; m <<= 1) { s += __shfl_xor(s, m); q += __shfl_xor(q, m); }
  __shared__ float sh[8];
  if ((t & 63) == 0) { sh[t >> 6] = s; sh[4 + (t >> 6)] = q; }
  __syncthreads();
  s = sh[0] + sh[1] + sh[2] + sh[3];
  q = sh[4] + sh[5] + sh[6] + sh[7];
  const float mu = s * (1.f / 1024.f);
  const float var = q * (1.f / 1024.f) - mu * mu;
  const float rs = rsqrtf(var + 1e-5f);
  const int c = t * 4;
  const float in[4] = {v.x, v.y, v.z, v.w};
  u16x4 o;
#pragma unroll
  for (int i = 0; i < 4; ++i) o[i] = f2bf((in[i] - mu) * rs * g[c + i] + bsh[c + i]);
  *(u16x4*)(y + row * 1024 + c) = o;
}

// ============ 256x256 MFMA GEMM, BK=32, 4-slot LDS ring, counted vmcnt =======
// One fence-set per K-tile: {vmcnt(8); s_barrier; sched_barrier(0)} then
// 12 ds_read_b128 + 4 global_load_lds + 32 MFMA in ONE region: the compiler
// inserts minimal counted lgkmcnt per read->MFMA dep, so LDS-read streaming
// overlaps the MFMA cluster (R4/R5's mid-tile BAR+lgkm0+SB0 fences serialized
// the LDS pipe (~1400cy) with the MFMA pipe (~1242cy) -> measured 2944cy/tile).
// Ring invariants unchanged (verified R3-R6): stage slot (T+3)&3 holds tile
// T-1, dead since the top barrier; 4 uniform stage-issues per tile (UNCLAMPED
// tail: tiles >= NT stage garbage from <=192B past the row -- in-buffer reads,
// landing in slots never read again), so at top of T, vmcnt(8) => tile T
// resident; barrier makes it collective.  All address math hoisted: slot-base
// pointers precomputed, (T&3) static via unroll-4, global stage ptrs bumped.
// T2 k-slot XOR swizzle both-sides (verified SQ_LDS_BANK_CONFLICT = 0).
// EPI 0: fused KV epilogue (col0<1024 -> K-path w/ rowssq+gain, else V-path)
// EPI 1: CK bf16 = gelu_exact(acc + biasK[col]), ldc = N.
template <int EPI, int KK>
__global__ __launch_bounds__(512, 2) void gemm256(
    const u16* __restrict__ A, const u16* __restrict__ Bt,
    const float* __restrict__ biasK, const float* __restrict__ biasV,
    const float* __restrict__ gcol, u16* __restrict__ CK, u16* __restrict__ CV,
    float* __restrict__ rowssq, int M, int N, int RB, int CB) {
  __shared__ u16 lds[4][16384];  // per slot: A tile [256][32] then B tile [256][32]
  const int t = threadIdx.x;
  const int lane = t & 63;
  const int wave = t >> 6;
  const int wm = wave >> 2, wn = wave & 3;
  const int fr = lane & 15, kq = lane >> 4;

  // XCD-aware swizzle (gridDim.x % 8 == 0 for all our shapes)
  const int bid = blockIdx.x;
  const int cpx = gridDim.x >> 3;
  const int swz = (bid & 7) * cpx + (bid >> 3);
  const int rb = swz / CB, cb = swz % CB;  // cb-fastest
  const size_t row0 = (size_t)rb * 256, col0 = (size_t)cb * 256;

  f4v acc[8][4];
#pragma unroll
  for (int i = 0; i < 8; ++i)
#pragma unroll
    for (int n = 0; n < 4; ++n) acc[i][n] = (f4v){0.f, 0.f, 0.f, 0.f};

  // staging: LDS dest linear (t*16B); global column pre-swizzled (rule 21)
  const int srow = t >> 2;
  const int scol = (((t & 3) ^ ((t >> 3) & 3)) << 3);
  const u16* Ag0 = A + (row0 + srow) * (size_t)KK + scol;
  const u16* Ag1 = Ag0 + (size_t)128 * KK;
  const u16* Bg0 = Bt + (col0 + srow) * (size_t)KK + scol;
  const u16* Bg1 = Bg0 + (size_t)128 * KK;

  // precomputed per-slot LDS base pointers (read side swizzled, write side dest)
  const int kxb = ((kq ^ ((fr >> 1) & 3)) << 4);  // byte offset of swizzled k-slot
  const char* lbase = (const char*)&lds[0][0];
  const char* bA[4];
  const char* bB[4];
  char* dst0[4];
#pragma unroll
  for (int s = 0; s < 4; ++s) {
    bA[s] = lbase + s * 32768 + wm * 8192 + fr * 64 + kxb;
    bB[s] = lbase + s * 32768 + 16384 + wn * 4096 + fr * 64 + kxb;
    dst0[s] = (char*)lbase + s * 32768 + t * 16;
  }

  // prologue: stage tiles 0..2 (12 loads; 4 per tile)
#pragma unroll
  for (int tt = 0; tt < 3; ++tt) {
    gload16(Ag0 + tt * 32, dst0[tt]);
    gload16(Ag1 + tt * 32, dst0[tt] + 8192);
    gload16(Bg0 + tt * 32, dst0[tt] + 16384);
    gload16(Bg1 + tt * 32, dst0[tt] + 24576);
  }

  const int NT = KK >> 5;
#pragma unroll 4
  for (int T = 0; T < NT; ++T) {
    asm volatile("s_waitcnt vmcnt(8)" ::: "memory");
    __builtin_amdgcn_s_barrier();
    __builtin_amdgcn_sched_barrier(0);
    const char* sA = bA[T & 3];
    const char* sB = bB[T & 3];
    s8v a0[4], a1[4], b[4];
#pragma unroll
    for (int m = 0; m < 4; ++m) {
      a0[m] = *(const s8v*)(sA + m * 1024);
      a1[m] = *(const s8v*)(sA + 4096 + m * 1024);
    }
#pragma unroll
    for (int n = 0; n < 4; ++n) b[n] = *(const s8v*)(sB + n * 1024);
    {  // stage tile T+3 (slot held tile T-1: dead since top barrier)
      char* d = dst0[(T + 3) & 3];
      gload16(Ag0 + (T + 3) * 32, d);
      gload16(Ag1 + (T + 3) * 32, d + 8192);
      gload16(Bg0 + (T + 3) * 32, d + 16384);
      gload16(Bg1 + (T + 3) * 32, d + 24576);
    }
    __builtin_amdgcn_s_setprio(1);
#pragma unroll
    for (int m = 0; m < 4; ++m)
#pragma unroll
      for (int n = 0; n < 4; ++n)
        acc[m][n] = __builtin_amdgcn_mfma_f32_16x16x32_bf16(a0[m], b[n], acc[m][n], 0, 0, 0);
#pragma unroll
    for (int m = 0; m < 4; ++m)
#pragma unroll
      for (int n = 0; n < 4; ++n)
        acc[4 + m][n] = __builtin_amdgcn_mfma_f32_16x16x32_bf16(a1[m], b[n], acc[4 + m][n], 0, 0, 0);
    __builtin_amdgcn_s_setprio(0);
  }

  // ---- epilogue ----
  const int kq4 = kq * 4;
  if (EPI == 0) {
    const bool isK = (col0 < 1024);
    if (isK) {
#pragma unroll
      for (int ai = 0; ai < 8; ++ai) {
        int cols[4];
        float bb[4], gg[4];
#pragma unroll
        for (int n = 0; n < 4; ++n) {
          cols[n] = (int)col0 + wn * 64 + n * 16 + fr;
          bb[n] = biasK[cols[n]];
          gg[n] = gcol[cols[n]];
        }
#pragma unroll
        for (int r = 0; r < 4; ++r) {
          const size_t grow = row0 + wm * 128 + ai * 16 + kq4 + r;
          float v[4];
#pragma unroll
          for (int n = 0; n < 4; ++n) v[n] = acc[ai][n][r] + bb[n];
          float s = v[0] * v[0] + v[1] * v[1] + v[2] * v[2] + v[3] * v[3];
          s += __shfl_xor(s, 1);
          s += __shfl_xor(s, 2);
          s += __shfl_xor(s, 4);
          s += __shfl_xor(s, 8);
          if (fr == 0) atomicAdd(&rowssq[grow], s);
#pragma unroll
          for (int n = 0; n < 4; ++n)
            CK[grow * 1024 + cols[n]] = f2bf(v[n] * gg[n]);
        }
      }
    } else {
#pragma unroll
      for (int ai = 0; ai < 8; ++ai) {
        int cols[4];
        float bb[4];
#pragma unroll
        for (int n = 0; n < 4; ++n) {
          cols[n] = (int)col0 - 1024 + wn * 64 + n * 16 + fr;
          bb[n] = biasV[cols[n]];
        }
#pragma unroll
        for (int r = 0; r < 4; ++r) {
          const size_t grow = row0 + wm * 128 + ai * 16 + kq4 + r;
#pragma unroll
          for (int n = 0; n < 4; ++n)
            CV[grow * 1024 + cols[n]] = f2bf(acc[ai][n][r] + bb[n]);
        }
      }
    }
  } else {
#pragma unroll
    for (int ai = 0; ai < 8; ++ai) {
      int cols[4];
      float bb[4];
#pragma unroll
      for (int n = 0; n < 4; ++n) {
        cols[n] = (int)col0 + wn * 64 + n * 16 + fr;
        bb[n] = biasK[cols[n]];
      }
#pragma unroll
      for (int r = 0; r < 4; ++r) {
        const size_t grow = row0 + wm * 128 + ai * 16 + kq4 + r;
#pragma unroll
        for (int n = 0; n < 4; ++n) {
          const float x = acc[ai][n][r] + bb[n];
          CK[grow * (size_t)N + cols[n]] = f2bf(0.5f * x * (1.f + erff(x * 0.70710678118654752f)));
        }
      }
    }
  }
}

// ---------------- 128x128 MFMA GEMM (m97 structure), epilogues ---------------
// EPI 3: store f32 (acc+bias+extra[row,col])
// EPI 5: v=acc+bias; atomic rowssq += v^2; store bf16 v   (q-path)
// EPI 6: split-K partial: store f32 raw acc to Cv + z*M*N; K-range by blockIdx.z
template <int EPI>
__global__ __launch_bounds__(256) void gemm_bt(
    const u16* __restrict__ A, const u16* __restrict__ Bt,
    const float* __restrict__ bias, const float* __restrict__ gcol,
    void* __restrict__ Cv, const float* __restrict__ extra,
    float* __restrict__ rowssq, int M, int N, int K) {
  __shared__ u16 As[128 * 32];
  __shared__ u16 Bs[128 * 32];
  const int t = threadIdx.x;
  const int lane = t & 63;
  const int wave = t >> 6;
  const int wr = wave >> 1, wc = wave & 1;
  const size_t row0 = (size_t)blockIdx.y * 128;
  const size_t col0 = (size_t)blockIdx.x * 128;
  int Ksub = K, koff = 0;
  if (EPI == 6) { Ksub = K / gridDim.z; koff = blockIdx.z * Ksub; }

  f4v acc[4][4];
#pragma unroll
  for (int m = 0; m < 4; ++m)
#pragma unroll
    for (int n = 0; n < 4; ++n) acc[m][n] = (f4v){0.f, 0.f, 0.f, 0.f};

  const int sr = t >> 2;
  const int scw = (((t & 3) ^ ((t >> 3) & 3)) << 3);  // pre-swizzled global col
  const u16* Ag = A + (row0 + sr) * (size_t)K + koff + scw;
  const u16* Bg = Bt + (col0 + sr) * (size_t)K + koff + scw;
  u16* Al = &As[t * 8];  // linear dest
  u16* Bl = &Bs[t * 8];
  const int fr = lane & 15;
  const int kx = (((lane >> 4) ^ ((fr >> 1) & 3)) << 3);

  for (int k0 = 0; k0 < Ksub; k0 += 32) {
    gload16(Ag + k0, Al);
    gload16(Ag + k0 + (size_t)64 * K, Al + 64 * 32);
    gload16(Bg + k0, Bl);
    gload16(Bg + k0 + (size_t)64 * K, Bl + 64 * 32);
    __syncthreads();
    s8v a[4], b[4];
#pragma unroll
    for (int m = 0; m < 4; ++m)
      a[m] = *(const s8v*)&As[(wr * 64 + m * 16 + fr) * 32 + kx];
#pragma unroll
    for (int n = 0; n < 4; ++n)
      b[n] = *(const s8v*)&Bs[(wc * 64 + n * 16 + fr) * 32 + kx];
#pragma unroll
    for (int m = 0; m < 4; ++m)
#pragma unroll
      for (int n = 0; n < 4; ++n)
        acc[m][n] = __builtin_amdgcn_mfma_f32_16x16x32_bf16(a[m], b[n], acc[m][n], 0, 0, 0);
    __syncthreads();
  }

  float* Cp = (float*)Cv;
  if (EPI == 6) Cp += (size_t)blockIdx.z * M * (size_t)N;
  const int rg = (lane >> 4) * 4;
#pragma unroll
  for (int m = 0; m < 4; ++m) {
    int cols[4];
    float bvals[4];
#pragma unroll
    for (int n = 0; n < 4; ++n) {
      cols[n] = (int)col0 + wc * 64 + n * 16 + fr;
      bvals[n] = (EPI == 6) ? 0.f : bias[cols[n]];
    }
#pragma unroll
    for (int r = 0; r < 4; ++r) {
      const size_t grow = row0 + wr * 64 + m * 16 + rg + r;
      float v[4];
#pragma unroll
      for (int n = 0; n < 4; ++n) v[n] = acc[m][n][r] + bvals[n];
      if (EPI == 5) {
        float s = v[0] * v[0] + v[1] * v[1] + v[2] * v[2] + v[3] * v[3];
        s += __shfl_xor(s, 1);
        s += __shfl_xor(s, 2);
        s += __shfl_xor(s, 4);
        s += __shfl_xor(s, 8);
        if (fr == 0) atomicAdd(&rowssq[grow], s);
      }
#pragma unroll
      for (int n = 0; n < 4; ++n) {
        const size_t idx = grow * (size_t)N + cols[n];
        if (EPI == 3) {
          Cp[idx] = v[n] + extra[idx];
        } else if (EPI == 5) {
          ((u16*)Cv)[idx] = f2bf(v[n]);
        } else if (EPI == 6) {
          Cp[idx] = v[n];
        }
      }
    }
  }
}

// ---------------- attention with the faithful raw-reshape semantics ----------
// head h, key j in [0,32): kv position = 2h + j/16, d-slice = (j%16)*64 .. +64
// q applied here: q_eff[d] = qpre[d]*gq[d]*rsq_q*0.125 (rms of q folded)
__global__ __launch_bounds__(256) void attn_k(const u16* __restrict__ qf,
                                              const u16* __restrict__ kmat,
                                              const float* __restrict__ kssq,
                                              const u16* __restrict__ vmat,
                                              const float* __restrict__ gq,
                                              const float* __restrict__ qssq,
                                              u16* __restrict__ ao) {
  const int lb = blockIdx.x;
  const int t = threadIdx.x;
  const int wave = t >> 6, lane = t & 63;
  const int j = lane & 31, half = lane >> 5;
  const float rq = rsqrtf(qssq[lb] * (1.f / 1024.f) + 1e-6f) * 0.125f;
  __shared__ float po[64][17];
#pragma unroll
  for (int hi = 0; hi < 4; ++hi) {
    const int h = wave * 4 + hi;
    const int krow = lb * 32 + 2 * h + (j >> 4);
    const u16* kp = kmat + (size_t)krow * 1024 + (j & 15) * 64 + half * 32;
    const u16* qp = qf + (size_t)lb * 1024 + h * 64 + half * 32;
    const float* gqp = gq + h * 64 + half * 32;
    float s = 0.f;
#pragma unroll
    for (int cc = 0; cc < 4; ++cc) {
      s8v qv = *(const s8v*)(qp + cc * 8);
      s8v kv = *(const s8v*)(kp + cc * 8);
#pragma unroll
      for (int e = 0; e < 8; ++e)
        s += bf2f((u16)qv[e]) * gqp[cc * 8 + e] * bf2f((u16)kv[e]);
    }
    s += __shfl_xor(s, 32);
    s *= rsqrtf(kssq[krow] * (1.f / 1024.f) + 1e-6f) * rq;
    float mx = s;
#pragma unroll
    for (int m = 16; m >= 1; m >>= 1) mx = fmaxf(mx, __shfl_xor(mx, m));
    const float pe = __expf(s - mx);
    float sum = pe;
#pragma unroll
    for (int m = 16; m >= 1; m >>= 1) sum += __shfl_xor(sum, m);
    const float pr = pe / sum;
    float o = 0.f;
#pragma unroll
    for (int jj = 0; jj < 32; ++jj) {
      const int vrow = lb * 32 + 2 * h + (jj >> 4);
      const float vv = bf2f(vmat[(size_t)vrow * 1024 + (jj & 15) * 64 + lane]);
      o += __shfl(pr, jj) * vv;
    }
    po[lane][h] = o;  // hd = lane
  }
  __syncthreads();
  const int c = t * 4;
  u16x4 o4;
#pragma unroll
  for (int i = 0; i < 4; ++i) o4[i] = f2bf(po[(c + i) >> 4][(c + i) & 15]);
  *(u16x4*)(ao + (size_t)lb * 1024 + c) = o4;
}

// ------------- W2 split-K combine: out = p0 + p1 + b2[col] + resid -----------
__global__ __launch_bounds__(256) void combine_k(const float* __restrict__ p0,
                                                 const float* __restrict__ p1,
                                                 const float* __restrict__ b2,
                                                 const float* __restrict__ resid,
                                                 float* __restrict__ out) {
  const int i = blockIdx.x * 256 + threadIdx.x;  // float4 index
  float4 a = ((const float4*)p0)[i];
  float4 b = ((const float4*)p1)[i];
  float4 r = ((const float4*)resid)[i];
  float4 bb = ((const float4*)b2)[i & 255];
  float4 o;
  o.x = a.x + b.x + r.x + bb.x;
  o.y = a.y + b.y + r.y + bb.y;
  o.z = a.z + b.z + r.z + bb.z;
  o.w = a.w + b.w + r.w + bb.w;
  ((float4*)out)[i] = o;
}

// -----------------------------------------------------------------------------
extern "C" void kernel_launch(void* const* d_in, const int* in_sizes, int n_in,
                              void* d_out, int out_size, void* d_ws, size_t ws_size,
                              hipStream_t stream) {
  const float* query  = (const float*)d_in[0];
  const float* pf     = (const float*)d_in[1];
  const float* lnq_g  = (const float*)d_in[2];
  const float* lnq_b  = (const float*)d_in[3];
  const float* lnkv_g = (const float*)d_in[4];
  const float* lnkv_b = (const float*)d_in[5];
  const float* Wq     = (const float*)d_in[6];
  const float* bq     = (const float*)d_in[7];
  const float* Wk     = (const float*)d_in[8];
  const float* bk     = (const float*)d_in[9];
  const float* Wv     = (const float*)d_in[10];
  const float* bv     = (const float*)d_in[11];
  const float* rmsq_g = (const float*)d_in[12];
  const float* rmsk_g = (const float*)d_in[13];
  const float* Wo     = (const float*)d_in[14];
  const float* bo     = (const float*)d_in[15];
  const float* mlpn_g = (const float*)d_in[16];
  const float* mlpn_b = (const float*)d_in[17];
  const float* W1     = (const float*)d_in[18];
  const float* b1     = (const float*)d_in[19];
  const float* W2     = (const float*)d_in[20];
  const float* b2     = (const float*)d_in[21];
  float* out = (float*)d_out;

  char* p = (char*)d_ws;
  auto alloc = [&](size_t n) {
    char* r = p;
    p += (n + 255) & ~(size_t)255;
    return r;
  };

  u16* Wqt = (u16*)alloc((size_t)1024 * 1024 * 2);
  u16* KVt = (u16*)alloc((size_t)2048 * 1024 * 2);  // [Wk^T ; Wv^T]
  u16* Wot = (u16*)alloc((size_t)1024 * 1024 * 2);
  u16* W1t = (u16*)alloc((size_t)1024 * 4096 * 2);
  u16* W2t = (u16*)alloc((size_t)4096 * 1024 * 2);
  u16* qln = (u16*)alloc((size_t)4096 * 1024 * 2);
  u16* qpre = (u16*)alloc((size_t)4096 * 1024 * 2);
  float* qssq = (float*)alloc((size_t)4096 * 4);
  u16* attn_o = (u16*)alloc((size_t)4096 * 1024 * 2);
  float* outbuf = (float*)alloc((size_t)4096 * 1024 * 4);
  u16* hbuf = (u16*)alloc((size_t)4096 * 1024 * 2);
  u16* mid = (u16*)alloc((size_t)4096 * 4096 * 2);
  float* w2p = (float*)alloc((size_t)2 * 4096 * 1024 * 4);  // split-K partials

  // chunked KV pipeline buffers (NC chunks; chunk data stays L3-resident)
  const size_t used = (size_t)(p - (char*)d_ws);
  int NC = 4;
  while (NC < 64) {
    size_t rows_try = (size_t)131072 / NC;
    if (used + 3 * (rows_try * 2048 + 256) + rows_try * 4 + 256 <= ws_size) break;
    NC *= 2;
  }
  const size_t rows = (size_t)131072 / NC;
  u16* kvln = (u16*)alloc(rows * 2048);
  u16* kmat = (u16*)alloc(rows * 2048);
  u16* vmat = (u16*)alloc(rows * 2048);
  float* kssq = (float*)alloc(rows * 4);

  // weight transpose+convert: W[K][N] f32 -> Wt[N][K] bf16
  transpose_w<<<dim3(32, 32), 256, 0, stream>>>(Wq, Wqt, 1024, 1024);
  transpose_w<<<dim3(32, 32), 256, 0, stream>>>(Wk, KVt, 1024, 1024);
  transpose_w<<<dim3(32, 32), 256, 0, stream>>>(Wv, KVt + (size_t)1024 * 1024, 1024, 1024);
  transpose_w<<<dim3(32, 32), 256, 0, stream>>>(Wo, Wot, 1024, 1024);
  transpose_w<<<dim3(128, 32), 256, 0, stream>>>(W1, W1t, 1024, 4096);
  transpose_w<<<dim3(32, 128), 256, 0, stream>>>(W2, W2t, 4096, 1024);

  // q path: LN -> GEMM(Wq)+bq (epilogue: bf16 qpre + qssq atomics)
  ln_rows<<<4096, 256, 0, stream>>>(query, lnq_g, lnq_b, qln, qssq);
  gemm_bt<5><<<dim3(8, 32), 256, 0, stream>>>(qln, Wqt, bq, nullptr, qpre, nullptr,
                                              qssq, 4096, 1024, 1024);

  // kv path: chunked ln -> fused K+V gemm256 -> attn (chunk stays in L3)
  const int bpc = 4096 / NC;
  const int RB = (int)(rows / 256);
  for (int c = 0; c < NC; ++c) {
    ln_rows<<<(unsigned)rows, 256, 0, stream>>>(pf + (size_t)c * rows * 1024, lnkv_g,
                                                lnkv_b, kvln, kssq);
    gemm256<0, 1024><<<RB * 8, 512, 0, stream>>>(kvln, KVt, bk, bv, rmsk_g, kmat, vmat,
                                                 kssq, (int)rows, 2048, RB, 8);
    attn_k<<<bpc, 256, 0, stream>>>(qpre + (size_t)c * bpc * 1024, kmat, kssq, vmat,
                                    rmsq_g, qssq + (size_t)c * bpc,
                                    attn_o + (size_t)c * bpc * 1024);
  }

  // out = attn_o @ Wo + bo + query  (f32)
  gemm_bt<3><<<dim3(8, 32), 256, 0, stream>>>(attn_o, Wot, bo, nullptr, outbuf, query,
                                              nullptr, 4096, 1024, 1024);
  // h = LN(out)
  ln_rows<<<4096, 256, 0, stream>>>(outbuf, mlpn_g, mlpn_b, hbuf, nullptr);
  // mid = gelu(h @ W1 + b1)  -- 256^2 kernel, grid 16x16
  gemm256<1, 1024><<<16 * 16, 512, 0, stream>>>(hbuf, W1t, b1, nullptr, nullptr, mid,
                                                nullptr, nullptr, 4096, 4096, 16, 16);
  // final = mid @ W2 (split-K=2 partials) + b2 + out
  gemm_bt<6><<<dim3(8, 32, 2), 256, 0, stream>>>(mid, W2t, nullptr, nullptr, w2p,
                                                 nullptr, nullptr, 4096, 1024, 4096);
  combine_k<<<4096, 256, 0, stream>>>(w2p, w2p + (size_t)4096 * 1024, b2, outbuf, out);
}

// Round 8
// 1062.297 us; speedup vs baseline: 1.0383x; 1.0075x over previous
//
#include <hip/hip_runtime.h>
#include <stdint.h>

#define DEVI __device__ __forceinline__

typedef unsigned short u16;
typedef short s8v __attribute__((ext_vector_type(8)));
typedef float f4v __attribute__((ext_vector_type(4)));
typedef u16 u16x4 __attribute__((ext_vector_type(4)));

DEVI u16 f2bf(float f) {
  unsigned u = __float_as_uint(f);
  u += 0x7fffu + ((u >> 16) & 1u);
  return (u16)(u >> 16);
}
DEVI float bf2f(u16 h) { return __uint_as_float(((unsigned)h) << 16); }

DEVI void gload16(const void* g, void* l) {
  __builtin_amdgcn_global_load_lds(
      (const __attribute__((address_space(1))) void*)(uintptr_t)g,
      (__attribute__((address_space(3))) void*)(uintptr_t)l, 16, 0, 0);
}

// ---------------- transpose + f32->bf16 convert: W[R][C] -> Wt[C][R] ----------
__global__ __launch_bounds__(256) void transpose_w(const float* __restrict__ W,
                                                   u16* __restrict__ Wt, int R, int C) {
  __shared__ float tile[32][33];
  const int tx = threadIdx.x & 31, ty = threadIdx.x >> 5;
  const int r0 = blockIdx.y * 32, c0 = blockIdx.x * 32;
#pragma unroll
  for (int i = 0; i < 4; ++i)
    tile[ty + 8 * i][tx] = W[(size_t)(r0 + ty + 8 * i) * C + c0 + tx];
  __syncthreads();
#pragma unroll
  for (int i = 0; i < 4; ++i)
    Wt[(size_t)(c0 + ty + 8 * i) * R + r0 + tx] = f2bf(tile[tx][ty + 8 * i]);
}

// ------- row LayerNorm (D=1024), f32 in -> bf16 out; optionally zero zbuf[row]
__global__ __launch_bounds__(256) void ln_rows(const float* __restrict__ x,
                                               const float* __restrict__ g,
                                               const float* __restrict__ bsh,
                                               u16* __restrict__ y,
                                               float* __restrict__ zbuf) {
  const size_t row = blockIdx.x;
  const int t = threadIdx.x;
  if (zbuf && t == 0) zbuf[row] = 0.f;
  float4 v = ((const float4*)(x + row * 1024))[t];
  float s = v.x + v.y + v.z + v.w;
  float q = v.x * v.x + v.y * v.y + v.z * v.z + v.w * v.w;
#pragma unroll
  for (int m = 1; m < 64; m <<= 1) { s += __shfl_xor(s, m); q += __shfl_xor(q, m); }
  __shared__ float sh[8];
  if ((t & 63) == 0) { sh[t >> 6] = s; sh[4 + (t >> 6)] = q; }
  __syncthreads();
  s = sh[0] + sh[1] + sh[2] + sh[3];
  q = sh[4] + sh[5] + sh[6] + sh[7];
  const float mu = s * (1.f / 1024.f);
  const float var = q * (1.f / 1024.f) - mu * mu;
  const float rs = rsqrtf(var + 1e-5f);
  const int c = t * 4;
  const float in[4] = {v.x, v.y, v.z, v.w};
  u16x4 o;
#pragma unroll
  for (int i = 0; i < 4; ++i) o[i] = f2bf((in[i] - mu) * rs * g[c + i] + bsh[c + i]);
  *(u16x4*)(y + row * 1024 + c) = o;
}

// ====== 256x256 MFMA GEMM, BK=32, 4-slot ring, CROSS-ITER REGISTER PIPELINE ==
// Iter T's 32 MFMAs consume A-fragments read in iter T-1 (a_cur) + B-frags
// read at top of iter T (stream under the MFMA cluster).  Iter T also reads
// tile T+1's A-frags into a_nxt (no consumer this iter -> fully overlapped).
// Residency: at top of iter T issued = 12+4T; vmcnt(4) => completed through
// tile T+1's stage; barrier makes it collective.  Slot-reuse: stage T+3 hits
// tile T-1's slot, whose reads completed before iter T-1's MFMA cluster
// (counted lgkm deps) hence before the top-of-T barrier.  Unclamped tail
// stages/reads touch only slots never consumed (in-arena reads, proven R6/R7).
// Static a_cur/a_nxt swap via manually paired loop (rule 20); slot indices
// static via #pragma unroll 2 of the pair loop (ring period 4).
// T2 k-slot XOR swizzle both-sides (verified SQ_LDS_BANK_CONFLICT = 0).
// EPI 0: fused KV epilogue (col0<1024 -> K-path w/ rowssq+gain, else V-path)
// EPI 1: CK bf16 = gelu_exact(acc + biasK[col]), ldc = N.
template <int EPI, int KK>
__global__ __launch_bounds__(512, 2) void gemm256(
    const u16* __restrict__ A, const u16* __restrict__ Bt,
    const float* __restrict__ biasK, const float* __restrict__ biasV,
    const float* __restrict__ gcol, u16* __restrict__ CK, u16* __restrict__ CV,
    float* __restrict__ rowssq, int M, int N, int RB, int CB) {
  __shared__ u16 lds[4][16384];  // per slot: A tile [256][32] then B tile [256][32]
  const int t = threadIdx.x;
  const int lane = t & 63;
  const int wave = t >> 6;
  const int wm = wave >> 2, wn = wave & 3;
  const int fr = lane & 15, kq = lane >> 4;

  const int bid = blockIdx.x;
  const int cpx = gridDim.x >> 3;
  const int swz = (bid & 7) * cpx + (bid >> 3);
  const int rb = swz / CB, cb = swz % CB;  // cb-fastest
  const size_t row0 = (size_t)rb * 256, col0 = (size_t)cb * 256;

  f4v acc[8][4];
#pragma unroll
  for (int i = 0; i < 8; ++i)
#pragma unroll
    for (int n = 0; n < 4; ++n) acc[i][n] = (f4v){0.f, 0.f, 0.f, 0.f};

  // staging: LDS dest linear (t*16B); global column pre-swizzled (rule 21)
  const int srow = t >> 2;
  const int scol = (((t & 3) ^ ((t >> 3) & 3)) << 3);
  const u16* Ag0 = A + (row0 + srow) * (size_t)KK + scol;
  const u16* Ag1 = Ag0 + (size_t)128 * KK;
  const u16* Bg0 = Bt + (col0 + srow) * (size_t)KK + scol;
  const u16* Bg1 = Bg0 + (size_t)128 * KK;

  // per-slot LDS base pointers (read side swizzled, write side linear dest)
  const int kxb = ((kq ^ ((fr >> 1) & 3)) << 4);  // byte offset of swizzled k-slot
  const char* lbase = (const char*)&lds[0][0];
  const char* bA[4];
  const char* bB[4];
  char* dst0[4];
#pragma unroll
  for (int s = 0; s < 4; ++s) {
    bA[s] = lbase + s * 32768 + wm * 8192 + fr * 64 + kxb;
    bB[s] = lbase + s * 32768 + 16384 + wn * 4096 + fr * 64 + kxb;
    dst0[s] = (char*)lbase + s * 32768 + t * 16;
  }

  // prologue: stage tiles 0..2 (12 loads; 4 per tile)
#pragma unroll
  for (int tt = 0; tt < 3; ++tt) {
    gload16(Ag0 + tt * 32, dst0[tt]);
    gload16(Ag1 + tt * 32, dst0[tt] + 8192);
    gload16(Bg0 + tt * 32, dst0[tt] + 16384);
    gload16(Bg1 + tt * 32, dst0[tt] + 24576);
  }

  s8v aX[8], aY[8], b[4];
  // preload tile 0 A-frags into aX
  asm volatile("s_waitcnt vmcnt(8)" ::: "memory");
  __builtin_amdgcn_s_barrier();
  __builtin_amdgcn_sched_barrier(0);
#pragma unroll
  for (int m = 0; m < 4; ++m) {
    aX[m] = *(const s8v*)(bA[0] + m * 1024);
    aX[4 + m] = *(const s8v*)(bA[0] + 4096 + m * 1024);
  }

#define GEMM_ITER(T_, CUR, NXT)                                                  \
  {                                                                              \
    asm volatile("s_waitcnt vmcnt(4)" ::: "memory");                             \
    __builtin_amdgcn_s_barrier();                                                \
    __builtin_amdgcn_sched_barrier(0);                                           \
    { /* stage tile T+3 into slot of dead tile T-1 */                            \
      char* d = dst0[(T_ + 3) & 3];                                              \
      gload16(Ag0 + (T_ + 3) * 32, d);                                           \
      gload16(Ag1 + (T_ + 3) * 32, d + 8192);                                    \
      gload16(Bg0 + (T_ + 3) * 32, d + 16384);                                   \
      gload16(Bg1 + (T_ + 3) * 32, d + 24576);                                   \
    }                                                                            \
    _Pragma("unroll") for (int n = 0; n < 4; ++n)                                \
        b[n] = *(const s8v*)(bB[T_ & 3] + n * 1024);                             \
    _Pragma("unroll") for (int m = 0; m < 4; ++m) {                              \
      NXT[m] = *(const s8v*)(bA[(T_ + 1) & 3] + m * 1024);                       \
      NXT[4 + m] = *(const s8v*)(bA[(T_ + 1) & 3] + 4096 + m * 1024);            \
    }                                                                            \
    __builtin_amdgcn_s_setprio(1);                                               \
    _Pragma("unroll") for (int m = 0; m < 4; ++m)                                \
        _Pragma("unroll") for (int n = 0; n < 4; ++n)                            \
            acc[m][n] =                                                          \
        __builtin_amdgcn_mfma_f32_16x16x32_bf16(CUR[m], b[n], acc[m][n], 0, 0, 0); \
    _Pragma("unroll") for (int m = 0; m < 4; ++m)                                \
        _Pragma("unroll") for (int n = 0; n < 4; ++n)                            \
            acc[4 + m][n] = __builtin_amdgcn_mfma_f32_16x16x32_bf16(             \
                CUR[4 + m], b[n], acc[4 + m][n], 0, 0, 0);                       \
    __builtin_amdgcn_s_setprio(0);                                               \
  }

  const int NT = KK >> 5;  // even (KK=1024 -> 32)
#pragma unroll 2
  for (int T = 0; T < NT; T += 2) {
    GEMM_ITER(T, aX, aY);
    GEMM_ITER((T + 1), aY, aX);
  }
#undef GEMM_ITER

  // ---- epilogue ----
  const int kq4 = kq * 4;
  if (EPI == 0) {
    const bool isK = (col0 < 1024);
    if (isK) {
#pragma unroll
      for (int ai = 0; ai < 8; ++ai) {
        int cols[4];
        float bb[4], gg[4];
#pragma unroll
        for (int n = 0; n < 4; ++n) {
          cols[n] = (int)col0 + wn * 64 + n * 16 + fr;
          bb[n] = biasK[cols[n]];
          gg[n] = gcol[cols[n]];
        }
#pragma unroll
        for (int r = 0; r < 4; ++r) {
          const size_t grow = row0 + wm * 128 + ai * 16 + kq4 + r;
          float v[4];
#pragma unroll
          for (int n = 0; n < 4; ++n) v[n] = acc[ai][n][r] + bb[n];
          float s = v[0] * v[0] + v[1] * v[1] + v[2] * v[2] + v[3] * v[3];
          s += __shfl_xor(s, 1);
          s += __shfl_xor(s, 2);
          s += __shfl_xor(s, 4);
          s += __shfl_xor(s, 8);
          if (fr == 0) atomicAdd(&rowssq[grow], s);
#pragma unroll
          for (int n = 0; n < 4; ++n)
            CK[grow * 1024 + cols[n]] = f2bf(v[n] * gg[n]);
        }
      }
    } else {
#pragma unroll
      for (int ai = 0; ai < 8; ++ai) {
        int cols[4];
        float bb[4];
#pragma unroll
        for (int n = 0; n < 4; ++n) {
          cols[n] = (int)col0 - 1024 + wn * 64 + n * 16 + fr;
          bb[n] = biasV[cols[n]];
        }
#pragma unroll
        for (int r = 0; r < 4; ++r) {
          const size_t grow = row0 + wm * 128 + ai * 16 + kq4 + r;
#pragma unroll
          for (int n = 0; n < 4; ++n)
            CV[grow * 1024 + cols[n]] = f2bf(acc[ai][n][r] + bb[n]);
        }
      }
    }
  } else {
#pragma unroll
    for (int ai = 0; ai < 8; ++ai) {
      int cols[4];
      float bb[4];
#pragma unroll
      for (int n = 0; n < 4; ++n) {
        cols[n] = (int)col0 + wn * 64 + n * 16 + fr;
        bb[n] = biasK[cols[n]];
      }
#pragma unroll
      for (int r = 0; r < 4; ++r) {
        const size_t grow = row0 + wm * 128 + ai * 16 + kq4 + r;
#pragma unroll
        for (int n = 0; n < 4; ++n) {
          const float x = acc[ai][n][r] + bb[n];
          CK[grow * (size_t)N + cols[n]] = f2bf(0.5f * x * (1.f + erff(x * 0.70710678118654752f)));
        }
      }
    }
  }
}

// ---------------- 128x128 MFMA GEMM (m97 structure), epilogues ---------------
// EPI 3: store f32 (acc+bias+extra[row,col])
// EPI 5: v=acc+bias; atomic rowssq += v^2; store bf16 v   (q-path)
// EPI 6: split-K partial: store f32 raw acc to Cv + z*M*N; K-range by blockIdx.z
template <int EPI>
__global__ __launch_bounds__(256) void gemm_bt(
    const u16* __restrict__ A, const u16* __restrict__ Bt,
    const float* __restrict__ bias, const float* __restrict__ gcol,
    void* __restrict__ Cv, const float* __restrict__ extra,
    float* __restrict__ rowssq, int M, int N, int K) {
  __shared__ u16 As[128 * 32];
  __shared__ u16 Bs[128 * 32];
  const int t = threadIdx.x;
  const int lane = t & 63;
  const int wave = t >> 6;
  const int wr = wave >> 1, wc = wave & 1;
  const size_t row0 = (size_t)blockIdx.y * 128;
  const size_t col0 = (size_t)blockIdx.x * 128;
  int Ksub = K, koff = 0;
  if (EPI == 6) { Ksub = K / gridDim.z; koff = blockIdx.z * Ksub; }

  f4v acc[4][4];
#pragma unroll
  for (int m = 0; m < 4; ++m)
#pragma unroll
    for (int n = 0; n < 4; ++n) acc[m][n] = (f4v){0.f, 0.f, 0.f, 0.f};

  const int sr = t >> 2;
  const int scw = (((t & 3) ^ ((t >> 3) & 3)) << 3);  // pre-swizzled global col
  const u16* Ag = A + (row0 + sr) * (size_t)K + koff + scw;
  const u16* Bg = Bt + (col0 + sr) * (size_t)K + koff + scw;
  u16* Al = &As[t * 8];  // linear dest
  u16* Bl = &Bs[t * 8];
  const int fr = lane & 15;
  const int kx = (((lane >> 4) ^ ((fr >> 1) & 3)) << 3);

  for (int k0 = 0; k0 < Ksub; k0 += 32) {
    gload16(Ag + k0, Al);
    gload16(Ag + k0 + (size_t)64 * K, Al + 64 * 32);
    gload16(Bg + k0, Bl);
    gload16(Bg + k0 + (size_t)64 * K, Bl + 64 * 32);
    __syncthreads();
    s8v a[4], b[4];
#pragma unroll
    for (int m = 0; m < 4; ++m)
      a[m] = *(const s8v*)&As[(wr * 64 + m * 16 + fr) * 32 + kx];
#pragma unroll
    for (int n = 0; n < 4; ++n)
      b[n] = *(const s8v*)&Bs[(wc * 64 + n * 16 + fr) * 32 + kx];
#pragma unroll
    for (int m = 0; m < 4; ++m)
#pragma unroll
      for (int n = 0; n < 4; ++n)
        acc[m][n] = __builtin_amdgcn_mfma_f32_16x16x32_bf16(a[m], b[n], acc[m][n], 0, 0, 0);
    __syncthreads();
  }

  float* Cp = (float*)Cv;
  if (EPI == 6) Cp += (size_t)blockIdx.z * M * (size_t)N;
  const int rg = (lane >> 4) * 4;
#pragma unroll
  for (int m = 0; m < 4; ++m) {
    int cols[4];
    float bvals[4];
#pragma unroll
    for (int n = 0; n < 4; ++n) {
      cols[n] = (int)col0 + wc * 64 + n * 16 + fr;
      bvals[n] = (EPI == 6) ? 0.f : bias[cols[n]];
    }
#pragma unroll
    for (int r = 0; r < 4; ++r) {
      const size_t grow = row0 + wr * 64 + m * 16 + rg + r;
      float v[4];
#pragma unroll
      for (int n = 0; n < 4; ++n) v[n] = acc[m][n][r] + bvals[n];
      if (EPI == 5) {
        float s = v[0] * v[0] + v[1] * v[1] + v[2] * v[2] + v[3] * v[3];
        s += __shfl_xor(s, 1);
        s += __shfl_xor(s, 2);
        s += __shfl_xor(s, 4);
        s += __shfl_xor(s, 8);
        if (fr == 0) atomicAdd(&rowssq[grow], s);
      }
#pragma unroll
      for (int n = 0; n < 4; ++n) {
        const size_t idx = grow * (size_t)N + cols[n];
        if (EPI == 3) {
          Cp[idx] = v[n] + extra[idx];
        } else if (EPI == 5) {
          ((u16*)Cv)[idx] = f2bf(v[n]);
        } else if (EPI == 6) {
          Cp[idx] = v[n];
        }
      }
    }
  }
}

// ---------------- attention with the faithful raw-reshape semantics ----------
// head h, key j in [0,32): kv position = 2h + j/16, d-slice = (j%16)*64 .. +64
// q applied here: q_eff[d] = qpre[d]*gq[d]*rsq_q*0.125 (rms of q folded)
__global__ __launch_bounds__(256) void attn_k(const u16* __restrict__ qf,
                                              const u16* __restrict__ kmat,
                                              const float* __restrict__ kssq,
                                              const u16* __restrict__ vmat,
                                              const float* __restrict__ gq,
                                              const float* __restrict__ qssq,
                                              u16* __restrict__ ao) {
  const int lb = blockIdx.x;
  const int t = threadIdx.x;
  const int wave = t >> 6, lane = t & 63;
  const int j = lane & 31, half = lane >> 5;
  const float rq = rsqrtf(qssq[lb] * (1.f / 1024.f) + 1e-6f) * 0.125f;
  __shared__ float po[64][17];
#pragma unroll
  for (int hi = 0; hi < 4; ++hi) {
    const int h = wave * 4 + hi;
    const int krow = lb * 32 + 2 * h + (j >> 4);
    const u16* kp = kmat + (size_t)krow * 1024 + (j & 15) * 64 + half * 32;
    const u16* qp = qf + (size_t)lb * 1024 + h * 64 + half * 32;
    const float* gqp = gq + h * 64 + half * 32;
    float s = 0.f;
#pragma unroll
    for (int cc = 0; cc < 4; ++cc) {
      s8v qv = *(const s8v*)(qp + cc * 8);
      s8v kv = *(const s8v*)(kp + cc * 8);
#pragma unroll
      for (int e = 0; e < 8; ++e)
        s += bf2f((u16)qv[e]) * gqp[cc * 8 + e] * bf2f((u16)kv[e]);
    }
    s += __shfl_xor(s, 32);
    s *= rsqrtf(kssq[krow] * (1.f / 1024.f) + 1e-6f) * rq;
    float mx = s;
#pragma unroll
    for (int m = 16; m >= 1; m >>= 1) mx = fmaxf(mx, __shfl_xor(mx, m));
    const float pe = __expf(s - mx);
    float sum = pe;
#pragma unroll
    for (int m = 16; m >= 1; m >>= 1) sum += __shfl_xor(sum, m);
    const float pr = pe / sum;
    float o = 0.f;
#pragma unroll
    for (int jj = 0; jj < 32; ++jj) {
      const int vrow = lb * 32 + 2 * h + (jj >> 4);
      const float vv = bf2f(vmat[(size_t)vrow * 1024 + (jj & 15) * 64 + lane]);
      o += __shfl(pr, jj) * vv;
    }
    po[lane][h] = o;  // hd = lane
  }
  __syncthreads();
  const int c = t * 4;
  u16x4 o4;
#pragma unroll
  for (int i = 0; i < 4; ++i) o4[i] = f2bf(po[(c + i) >> 4][(c + i) & 15]);
  *(u16x4*)(ao + (size_t)lb * 1024 + c) = o4;
}

// ------------- W2 split-K combine: out = p0 + p1 + b2[col] + resid -----------
__global__ __launch_bounds__(256) void combine_k(const float* __restrict__ p0,
                                                 const float* __restrict__ p1,
                                                 const float* __restrict__ b2,
                                                 const float* __restrict__ resid,
                                                 float* __restrict__ out) {
  const int i = blockIdx.x * 256 + threadIdx.x;  // float4 index
  float4 a = ((const float4*)p0)[i];
  float4 b = ((const float4*)p1)[i];
  float4 r = ((const float4*)resid)[i];
  float4 bb = ((const float4*)b2)[i & 255];
  float4 o;
  o.x = a.x + b.x + r.x + bb.x;
  o.y = a.y + b.y + r.y + bb.y;
  o.z = a.z + b.z + r.z + bb.z;
  o.w = a.w + b.w + r.w + bb.w;
  ((float4*)out)[i] = o;
}

// -----------------------------------------------------------------------------
extern "C" void kernel_launch(void* const* d_in, const int* in_sizes, int n_in,
                              void* d_out, int out_size, void* d_ws, size_t ws_size,
                              hipStream_t stream) {
  const float* query  = (const float*)d_in[0];
  const float* pf     = (const float*)d_in[1];
  const float* lnq_g  = (const float*)d_in[2];
  const float* lnq_b  = (const float*)d_in[3];
  const float* lnkv_g = (const float*)d_in[4];
  const float* lnkv_b = (const float*)d_in[5];
  const float* Wq     = (const float*)d_in[6];
  const float* bq     = (const float*)d_in[7];
  const float* Wk     = (const float*)d_in[8];
  const float* bk     = (const float*)d_in[9];
  const float* Wv     = (const float*)d_in[10];
  const float* bv     = (const float*)d_in[11];
  const float* rmsq_g = (const float*)d_in[12];
  const float* rmsk_g = (const float*)d_in[13];
  const float* Wo     = (const float*)d_in[14];
  const float* bo     = (const float*)d_in[15];
  const float* mlpn_g = (const float*)d_in[16];
  const float* mlpn_b = (const float*)d_in[17];
  const float* W1     = (const float*)d_in[18];
  const float* b1     = (const float*)d_in[19];
  const float* W2     = (const float*)d_in[20];
  const float* b2     = (const float*)d_in[21];
  float* out = (float*)d_out;

  char* p = (char*)d_ws;
  auto alloc = [&](size_t n) {
    char* r = p;
    p += (n + 255) & ~(size_t)255;
    return r;
  };

  u16* Wqt = (u16*)alloc((size_t)1024 * 1024 * 2);
  u16* KVt = (u16*)alloc((size_t)2048 * 1024 * 2);  // [Wk^T ; Wv^T]
  u16* Wot = (u16*)alloc((size_t)1024 * 1024 * 2);
  u16* W1t = (u16*)alloc((size_t)1024 * 4096 * 2);
  u16* W2t = (u16*)alloc((size_t)4096 * 1024 * 2);
  u16* qln = (u16*)alloc((size_t)4096 * 1024 * 2);
  u16* qpre = (u16*)alloc((size_t)4096 * 1024 * 2);
  float* qssq = (float*)alloc((size_t)4096 * 4);
  u16* attn_o = (u16*)alloc((size_t)4096 * 1024 * 2);
  float* outbuf = (float*)alloc((size_t)4096 * 1024 * 4);
  u16* hbuf = (u16*)alloc((size_t)4096 * 1024 * 2);
  u16* mid = (u16*)alloc((size_t)4096 * 4096 * 2);
  float* w2p = (float*)alloc((size_t)2 * 4096 * 1024 * 4);  // split-K partials

  // chunked KV pipeline buffers (NC chunks; chunk data stays L3-resident)
  const size_t used = (size_t)(p - (char*)d_ws);
  int NC = 4;
  while (NC < 64) {
    size_t rows_try = (size_t)131072 / NC;
    if (used + 3 * (rows_try * 2048 + 256) + rows_try * 4 + 256 <= ws_size) break;
    NC *= 2;
  }
  const size_t rows = (size_t)131072 / NC;
  u16* kvln = (u16*)alloc(rows * 2048);
  u16* kmat = (u16*)alloc(rows * 2048);
  u16* vmat = (u16*)alloc(rows * 2048);
  float* kssq = (float*)alloc(rows * 4);

  // weight transpose+convert: W[K][N] f32 -> Wt[N][K] bf16
  transpose_w<<<dim3(32, 32), 256, 0, stream>>>(Wq, Wqt, 1024, 1024);
  transpose_w<<<dim3(32, 32), 256, 0, stream>>>(Wk, KVt, 1024, 1024);
  transpose_w<<<dim3(32, 32), 256, 0, stream>>>(Wv, KVt + (size_t)1024 * 1024, 1024, 1024);
  transpose_w<<<dim3(32, 32), 256, 0, stream>>>(Wo, Wot, 1024, 1024);
  transpose_w<<<dim3(128, 32), 256, 0, stream>>>(W1, W1t, 1024, 4096);
  transpose_w<<<dim3(32, 128), 256, 0, stream>>>(W2, W2t, 4096, 1024);

  // q path: LN -> GEMM(Wq)+bq (epilogue: bf16 qpre + qssq atomics)
  ln_rows<<<4096, 256, 0, stream>>>(query, lnq_g, lnq_b, qln, qssq);
  gemm_bt<5><<<dim3(8, 32), 256, 0, stream>>>(qln, Wqt, bq, nullptr, qpre, nullptr,
                                              qssq, 4096, 1024, 1024);

  // kv path: chunked ln -> fused K+V gemm256 -> attn (chunk stays in L3)
  const int bpc = 4096 / NC;
  const int RB = (int)(rows / 256);
  for (int c = 0; c < NC; ++c) {
    ln_rows<<<(unsigned)rows, 256, 0, stream>>>(pf + (size_t)c * rows * 1024, lnkv_g,
                                                lnkv_b, kvln, kssq);
    gemm256<0, 1024><<<RB * 8, 512, 0, stream>>>(kvln, KVt, bk, bv, rmsk_g, kmat, vmat,
                                                 kssq, (int)rows, 2048, RB, 8);
    attn_k<<<bpc, 256, 0, stream>>>(qpre + (size_t)c * bpc * 1024, kmat, kssq, vmat,
                                    rmsq_g, qssq + (size_t)c * bpc,
                                    attn_o + (size_t)c * bpc * 1024);
  }

  // out = attn_o @ Wo + bo + query  (f32)
  gemm_bt<3><<<dim3(8, 32), 256, 0, stream>>>(attn_o, Wot, bo, nullptr, outbuf, query,
                                              nullptr, 4096, 1024, 1024);
  // h = LN(out)
  ln_rows<<<4096, 256, 0, stream>>>(outbuf, mlpn_g, mlpn_b, hbuf, nullptr);
  // mid = gelu(h @ W1 + b1)  -- 256^2 kernel, grid 16x16
  gemm256<1, 1024><<<16 * 16, 512, 0, stream>>>(hbuf, W1t, b1, nullptr, nullptr, mid,
                                                nullptr, nullptr, 4096, 4096, 16, 16);
  // final = mid @ W2 (split-K=2 partials) + b2 + out
  gemm_bt<6><<<dim3(8, 32, 2), 256, 0, stream>>>(mid, W2t, nullptr, nullptr, w2p,
                                                 nullptr, nullptr, 4096, 1024, 4096);
  combine_k<<<4096, 256, 0, stream>>>(w2p, w2p + (size_t)4096 * 1024, b2, outbuf, out);
}

// Round 9
// 1038.071 us; speedup vs baseline: 1.0625x; 1.0233x over previous
//
#include <hip/hip_runtime.h>
#include <stdint.h>

#define DEVI __device__ __forceinline__

typedef unsigned short u16;
typedef short s8v __attribute__((ext_vector_type(8)));
typedef float f4v __attribute__((ext_vector_type(4)));
typedef u16 u16x4 __attribute__((ext_vector_type(4)));

DEVI u16 f2bf(float f) {
  unsigned u = __float_as_uint(f);
  u += 0x7fffu + ((u >> 16) & 1u);
  return (u16)(u >> 16);
}
DEVI float bf2f(u16 h) { return __uint_as_float(((unsigned)h) << 16); }

DEVI void gload16(const void* g, void* l) {
  __builtin_amdgcn_global_load_lds(
      (const __attribute__((address_space(1))) void*)(uintptr_t)g,
      (__attribute__((address_space(3))) void*)(uintptr_t)l, 16, 0, 0);
}

// ---------------- transpose + f32->bf16 convert: W[R][C] -> Wt[C][R] ----------
__global__ __launch_bounds__(256) void transpose_w(const float* __restrict__ W,
                                                   u16* __restrict__ Wt, int R, int C) {
  __shared__ float tile[32][33];
  const int tx = threadIdx.x & 31, ty = threadIdx.x >> 5;
  const int r0 = blockIdx.y * 32, c0 = blockIdx.x * 32;
#pragma unroll
  for (int i = 0; i < 4; ++i)
    tile[ty + 8 * i][tx] = W[(size_t)(r0 + ty + 8 * i) * C + c0 + tx];
  __syncthreads();
#pragma unroll
  for (int i = 0; i < 4; ++i)
    Wt[(size_t)(c0 + ty + 8 * i) * R + r0 + tx] = f2bf(tile[tx][ty + 8 * i]);
}

// ------- row LayerNorm (D=1024), f32 in -> bf16 out; optionally zero zbuf[row]
__global__ __launch_bounds__(256) void ln_rows(const float* __restrict__ x,
                                               const float* __restrict__ g,
                                               const float* __restrict__ bsh,
                                               u16* __restrict__ y,
                                               float* __restrict__ zbuf) {
  const size_t row = blockIdx.x;
  const int t = threadIdx.x;
  if (zbuf && t == 0) zbuf[row] = 0.f;
  float4 v = ((const float4*)(x + row * 1024))[t];
  float s = v.x + v.y + v.z + v.w;
  float q = v.x * v.x + v.y * v.y + v.z * v.z + v.w * v.w;
#pragma unroll
  for (int m = 1; m < 64; m <<= 1) { s += __shfl_xor(s, m); q += __shfl_xor(q, m); }
  __shared__ float sh[8];
  if ((t & 63) == 0) { sh[t >> 6] = s; sh[4 + (t >> 6)] = q; }
  __syncthreads();
  s = sh[0] + sh[1] + sh[2] + sh[3];
  q = sh[4] + sh[5] + sh[6] + sh[7];
  const float mu = s * (1.f / 1024.f);
  const float var = q * (1.f / 1024.f) - mu * mu;
  const float rs = rsqrtf(var + 1e-5f);
  const int c = t * 4;
  const float in[4] = {v.x, v.y, v.z, v.w};
  u16x4 o;
#pragma unroll
  for (int i = 0; i < 4; ++i) o[i] = f2bf((in[i] - mu) * rs * g[c + i] + bsh[c + i]);
  *(u16x4*)(y + row * 1024 + c) = o;
}

// ====== 256x256 MFMA GEMM, BK=64, 2-slot dbuf, 4 phases/tile (m201 shape) ====
// Per K-tile (64): 4 phases {ds_read 4-12 | 2 gload_lds (1/4 of tile T+1) |
// setprio1 | 16 MFMA | setprio0}, NO mid-tile fences (plain-C++ reads ->
// compiler counted lgkm waits); ONE {vmcnt(0); s_barrier; sched_barrier(0)}
// per tile.  Quadrants (mh,nh): (0,0)->(0,1)->(1,1)->(1,0), separate b0/b1
// reg sets -> minimal 24 ds_read/wave/tile.  Slot safety: stage targets slot
// (T+1)&1 whose tile T-1 reads finished before the top-of-T fence; drain
// vmcnt(0) sits ~4 phases after the stage issues.  Tail: clamp restage of
// tile NT-1 into the dead slot.
// Swizzle (128-B rows): LDS[r][chunk c] holds global k-chunk c^(r&7).
// Write: linear LDS dest + pre-swizzled global col ((t&7)^((t>>3)&7))*8.
// Read: chunk byte-offsets kx0 = ((kq^(fr&7))<<4), kx1 = kx0^64.
// EPI 0: fused KV epilogue (col0<1024 -> K-path w/ rowssq+gain, else V-path)
// EPI 1: CK bf16 = gelu_exact(acc + biasK[col]), ldc = N.
template <int EPI, int KK>
__global__ __launch_bounds__(512, 2) void gemm256(
    const u16* __restrict__ A, const u16* __restrict__ Bt,
    const float* __restrict__ biasK, const float* __restrict__ biasV,
    const float* __restrict__ gcol, u16* __restrict__ CK, u16* __restrict__ CV,
    float* __restrict__ rowssq, int M, int N, int RB, int CB) {
  __shared__ u16 lds[2][32768];  // slot: A [256][64] (32KB) then B [256][64]
  const int t = threadIdx.x;
  const int lane = t & 63;
  const int wave = t >> 6;
  const int wm = wave >> 2, wn = wave & 3;
  const int fr = lane & 15, kq = lane >> 4;

  const int bid = blockIdx.x;
  const int cpx = gridDim.x >> 3;
  const int swz = (bid & 7) * cpx + (bid >> 3);
  const int rb = swz / CB, cb = swz % CB;  // cb-fastest
  const size_t row0 = (size_t)rb * 256, col0 = (size_t)cb * 256;

  f4v acc[8][4];
#pragma unroll
  for (int i = 0; i < 8; ++i)
#pragma unroll
    for (int n = 0; n < 4; ++n) acc[i][n] = (f4v){0.f, 0.f, 0.f, 0.f};

  // stage addressing: thread t -> row (t>>3)+j*64, LDS chunk t&7 (linear dest),
  // global chunk pre-swizzled
  const int srow = t >> 3;
  const int scol = (((t & 7) ^ (srow & 7)) << 3);
  const u16* Ag = A + (row0 + srow) * (size_t)KK + scol;
  const u16* Bg = Bt + (col0 + srow) * (size_t)KK + scol;
  char* dA[2];
  char* dB[2];
  const char* lb = (const char*)&lds[0][0];
#pragma unroll
  for (int s = 0; s < 2; ++s) {
    dA[s] = (char*)lb + s * 65536 + t * 16;
    dB[s] = (char*)lb + s * 65536 + 32768 + t * 16;
  }

  // read bases: A row = wm*128 + mh*64 + m*16 + fr; B row = wn*64 + nh*32 + n*16 + fr
  const int f7 = fr & 7;
  const int kx0 = ((kq ^ f7) << 4);
  const int kx1 = kx0 ^ 64;
  const char* bA[2][2];
  const char* bB[2][2];
#pragma unroll
  for (int s = 0; s < 2; ++s) {
    bA[s][0] = lb + s * 65536 + (wm * 128 + fr) * 128 + kx0;
    bA[s][1] = lb + s * 65536 + (wm * 128 + fr) * 128 + kx1;
    bB[s][0] = lb + s * 65536 + 32768 + (wn * 64 + fr) * 128 + kx0;
    bB[s][1] = lb + s * 65536 + 32768 + (wn * 64 + fr) * 128 + kx1;
  }

  const int NT = KK >> 6;  // BK=64; even for KK=1024 (16)

  // prologue: stage tile 0 into slot 0 (8 gloads: A quarters then B quarters)
#pragma unroll
  for (int j = 0; j < 4; ++j) {
    gload16(Ag + (size_t)j * 64 * KK, dA[0] + j * 8192);
    gload16(Bg + (size_t)j * 64 * KK, dB[0] + j * 8192);
  }
  asm volatile("s_waitcnt vmcnt(0)" ::: "memory");
  __builtin_amdgcn_s_barrier();
  __builtin_amdgcn_sched_barrier(0);

#define KV_ITER(T_, SL, SN)                                                      \
  {                                                                              \
    const int Ts = (T_ + 1 < NT) ? T_ + 1 : NT - 1;                              \
    const u16* Agt = Ag + (size_t)Ts * 64;                                       \
    const u16* Bgt = Bg + (size_t)Ts * 64;                                       \
    s8v a[8], b0[4], b1[4];                                                      \
    /* ---- ph0: quadrant (mh0,nh0) ---- */                                      \
    _Pragma("unroll") for (int m = 0; m < 4; ++m) {                              \
      a[2 * m] = *(const s8v*)(bA[SL][0] + m * 2048);                            \
      a[2 * m + 1] = *(const s8v*)(bA[SL][1] + m * 2048);                        \
    }                                                                            \
    _Pragma("unroll") for (int n = 0; n < 2; ++n) {                              \
      b0[2 * n] = *(const s8v*)(bB[SL][0] + n * 2048);                           \
      b0[2 * n + 1] = *(const s8v*)(bB[SL][1] + n * 2048);                       \
    }                                                                            \
    gload16(Agt, dA[SN]);                                                        \
    gload16(Agt + (size_t)64 * KK, dA[SN] + 8192);                               \
    __builtin_amdgcn_s_setprio(1);                                               \
    _Pragma("unroll") for (int m = 0; m < 4; ++m)                                \
        _Pragma("unroll") for (int n = 0; n < 2; ++n) {                          \
      acc[m][n] = __builtin_amdgcn_mfma_f32_16x16x32_bf16(a[2 * m], b0[2 * n],   \
                                                          acc[m][n], 0, 0, 0);   \
      acc[m][n] = __builtin_amdgcn_mfma_f32_16x16x32_bf16(                       \
          a[2 * m + 1], b0[2 * n + 1], acc[m][n], 0, 0, 0);                      \
    }                                                                            \
    __builtin_amdgcn_s_setprio(0);                                               \
    /* ---- ph1: quadrant (mh0,nh1) ---- */                                      \
    _Pragma("unroll") for (int n = 0; n < 2; ++n) {                              \
      b1[2 * n] = *(const s8v*)(bB[SL][0] + 4096 + n * 2048);                    \
      b1[2 * n + 1] = *(const s8v*)(bB[SL][1] + 4096 + n * 2048);                \
    }                                                                            \
    gload16(Agt + (size_t)128 * KK, dA[SN] + 16384);                             \
    gload16(Agt + (size_t)192 * KK, dA[SN] + 24576);                             \
    __builtin_amdgcn_s_setprio(1);                                               \
    _Pragma("unroll") for (int m = 0; m < 4; ++m)                                \
        _Pragma("unroll") for (int n = 0; n < 2; ++n) {                          \
      acc[m][2 + n] = __builtin_amdgcn_mfma_f32_16x16x32_bf16(                   \
          a[2 * m], b1[2 * n], acc[m][2 + n], 0, 0, 0);                          \
      acc[m][2 + n] = __builtin_amdgcn_mfma_f32_16x16x32_bf16(                   \
          a[2 * m + 1], b1[2 * n + 1], acc[m][2 + n], 0, 0, 0);                  \
    }                                                                            \
    __builtin_amdgcn_s_setprio(0);                                               \
    /* ---- ph2: quadrant (mh1,nh1), overwrite a ---- */                         \
    _Pragma("unroll") for (int m = 0; m < 4; ++m) {                              \
      a[2 * m] = *(const s8v*)(bA[SL][0] + 8192 + m * 2048);                     \
      a[2 * m + 1] = *(const s8v*)(bA[SL][1] + 8192 + m * 2048);                 \
    }                                                                            \
    gload16(Bgt, dB[SN]);                                                        \
    gload16(Bgt + (size_t)64 * KK, dB[SN] + 8192);                               \
    __builtin_amdgcn_s_setprio(1);                                               \
    _Pragma("unroll") for (int m = 0; m < 4; ++m)                                \
        _Pragma("unroll") for (int n = 0; n < 2; ++n) {                          \
      acc[4 + m][2 + n] = __builtin_amdgcn_mfma_f32_16x16x32_bf16(               \
          a[2 * m], b1[2 * n], acc[4 + m][2 + n], 0, 0, 0);                      \
      acc[4 + m][2 + n] = __builtin_amdgcn_mfma_f32_16x16x32_bf16(               \
          a[2 * m + 1], b1[2 * n + 1], acc[4 + m][2 + n], 0, 0, 0);              \
    }                                                                            \
    __builtin_amdgcn_s_setprio(0);                                               \
    /* ---- ph3: quadrant (mh1,nh0), b0 still live ---- */                       \
    gload16(Bgt + (size_t)128 * KK, dB[SN] + 16384);                             \
    gload16(Bgt + (size_t)192 * KK, dB[SN] + 24576);                             \
    __builtin_amdgcn_s_setprio(1);                                               \
    _Pragma("unroll") for (int m = 0; m < 4; ++m)                                \
        _Pragma("unroll") for (int n = 0; n < 2; ++n) {                          \
      acc[4 + m][n] = __builtin_amdgcn_mfma_f32_16x16x32_bf16(                   \
          a[2 * m], b0[2 * n], acc[4 + m][n], 0, 0, 0);                          \
      acc[4 + m][n] = __builtin_amdgcn_mfma_f32_16x16x32_bf16(                   \
          a[2 * m + 1], b0[2 * n + 1], acc[4 + m][n], 0, 0, 0);                  \
    }                                                                            \
    __builtin_amdgcn_s_setprio(0);                                               \
    asm volatile("s_waitcnt vmcnt(0)" ::: "memory");                             \
    __builtin_amdgcn_s_barrier();                                                \
    __builtin_amdgcn_sched_barrier(0);                                           \
  }

  for (int T = 0; T < NT; T += 2) {
    KV_ITER(T, 0, 1);
    KV_ITER((T + 1), 1, 0);
  }
#undef KV_ITER

  // ---- epilogue ----
  const int kq4 = kq * 4;
  if (EPI == 0) {
    const bool isK = (col0 < 1024);
    if (isK) {
#pragma unroll
      for (int ai = 0; ai < 8; ++ai) {
        int cols[4];
        float bb[4], gg[4];
#pragma unroll
        for (int n = 0; n < 4; ++n) {
          cols[n] = (int)col0 + wn * 64 + n * 16 + fr;
          bb[n] = biasK[cols[n]];
          gg[n] = gcol[cols[n]];
        }
#pragma unroll
        for (int r = 0; r < 4; ++r) {
          const size_t grow = row0 + wm * 128 + ai * 16 + kq4 + r;
          float v[4];
#pragma unroll
          for (int n = 0; n < 4; ++n) v[n] = acc[ai][n][r] + bb[n];
          float s = v[0] * v[0] + v[1] * v[1] + v[2] * v[2] + v[3] * v[3];
          s += __shfl_xor(s, 1);
          s += __shfl_xor(s, 2);
          s += __shfl_xor(s, 4);
          s += __shfl_xor(s, 8);
          if (fr == 0) atomicAdd(&rowssq[grow], s);
#pragma unroll
          for (int n = 0; n < 4; ++n)
            CK[grow * 1024 + cols[n]] = f2bf(v[n] * gg[n]);
        }
      }
    } else {
#pragma unroll
      for (int ai = 0; ai < 8; ++ai) {
        int cols[4];
        float bb[4];
#pragma unroll
        for (int n = 0; n < 4; ++n) {
          cols[n] = (int)col0 - 1024 + wn * 64 + n * 16 + fr;
          bb[n] = biasV[cols[n]];
        }
#pragma unroll
        for (int r = 0; r < 4; ++r) {
          const size_t grow = row0 + wm * 128 + ai * 16 + kq4 + r;
#pragma unroll
          for (int n = 0; n < 4; ++n)
            CV[grow * 1024 + cols[n]] = f2bf(acc[ai][n][r] + bb[n]);
        }
      }
    }
  } else {
#pragma unroll
    for (int ai = 0; ai < 8; ++ai) {
      int cols[4];
      float bb[4];
#pragma unroll
      for (int n = 0; n < 4; ++n) {
        cols[n] = (int)col0 + wn * 64 + n * 16 + fr;
        bb[n] = biasK[cols[n]];
      }
#pragma unroll
      for (int r = 0; r < 4; ++r) {
        const size_t grow = row0 + wm * 128 + ai * 16 + kq4 + r;
#pragma unroll
        for (int n = 0; n < 4; ++n) {
          const float x = acc[ai][n][r] + bb[n];
          CK[grow * (size_t)N + cols[n]] = f2bf(0.5f * x * (1.f + erff(x * 0.70710678118654752f)));
        }
      }
    }
  }
}

// ---------------- 128x128 MFMA GEMM (m97 structure), epilogues ---------------
// EPI 3: store f32 (acc+bias+extra[row,col])
// EPI 5: v=acc+bias; atomic rowssq += v^2; store bf16 v   (q-path)
// EPI 6: split-K partial: store f32 raw acc to Cv + z*M*N; K-range by blockIdx.z
template <int EPI>
__global__ __launch_bounds__(256) void gemm_bt(
    const u16* __restrict__ A, const u16* __restrict__ Bt,
    const float* __restrict__ bias, const float* __restrict__ gcol,
    void* __restrict__ Cv, const float* __restrict__ extra,
    float* __restrict__ rowssq, int M, int N, int K) {
  __shared__ u16 As[128 * 32];
  __shared__ u16 Bs[128 * 32];
  const int t = threadIdx.x;
  const int lane = t & 63;
  const int wave = t >> 6;
  const int wr = wave >> 1, wc = wave & 1;
  const size_t row0 = (size_t)blockIdx.y * 128;
  const size_t col0 = (size_t)blockIdx.x * 128;
  int Ksub = K, koff = 0;
  if (EPI == 6) { Ksub = K / gridDim.z; koff = blockIdx.z * Ksub; }

  f4v acc[4][4];
#pragma unroll
  for (int m = 0; m < 4; ++m)
#pragma unroll
    for (int n = 0; n < 4; ++n) acc[m][n] = (f4v){0.f, 0.f, 0.f, 0.f};

  const int sr = t >> 2;
  const int scw = (((t & 3) ^ ((t >> 3) & 3)) << 3);  // pre-swizzled global col
  const u16* Ag = A + (row0 + sr) * (size_t)K + koff + scw;
  const u16* Bg = Bt + (col0 + sr) * (size_t)K + koff + scw;
  u16* Al = &As[t * 8];  // linear dest
  u16* Bl = &Bs[t * 8];
  const int fr = lane & 15;
  const int kx = (((lane >> 4) ^ ((fr >> 1) & 3)) << 3);

  for (int k0 = 0; k0 < Ksub; k0 += 32) {
    gload16(Ag + k0, Al);
    gload16(Ag + k0 + (size_t)64 * K, Al + 64 * 32);
    gload16(Bg + k0, Bl);
    gload16(Bg + k0 + (size_t)64 * K, Bl + 64 * 32);
    __syncthreads();
    s8v a[4], b[4];
#pragma unroll
    for (int m = 0; m < 4; ++m)
      a[m] = *(const s8v*)&As[(wr * 64 + m * 16 + fr) * 32 + kx];
#pragma unroll
    for (int n = 0; n < 4; ++n)
      b[n] = *(const s8v*)&Bs[(wc * 64 + n * 16 + fr) * 32 + kx];
#pragma unroll
    for (int m = 0; m < 4; ++m)
#pragma unroll
      for (int n = 0; n < 4; ++n)
        acc[m][n] = __builtin_amdgcn_mfma_f32_16x16x32_bf16(a[m], b[n], acc[m][n], 0, 0, 0);
    __syncthreads();
  }

  float* Cp = (float*)Cv;
  if (EPI == 6) Cp += (size_t)blockIdx.z * M * (size_t)N;
  const int rg = (lane >> 4) * 4;
#pragma unroll
  for (int m = 0; m < 4; ++m) {
    int cols[4];
    float bvals[4];
#pragma unroll
    for (int n = 0; n < 4; ++n) {
      cols[n] = (int)col0 + wc * 64 + n * 16 + fr;
      bvals[n] = (EPI == 6) ? 0.f : bias[cols[n]];
    }
#pragma unroll
    for (int r = 0; r < 4; ++r) {
      const size_t grow = row0 + wr * 64 + m * 16 + rg + r;
      float v[4];
#pragma unroll
      for (int n = 0; n < 4; ++n) v[n] = acc[m][n][r] + bvals[n];
      if (EPI == 5) {
        float s = v[0] * v[0] + v[1] * v[1] + v[2] * v[2] + v[3] * v[3];
        s += __shfl_xor(s, 1);
        s += __shfl_xor(s, 2);
        s += __shfl_xor(s, 4);
        s += __shfl_xor(s, 8);
        if (fr == 0) atomicAdd(&rowssq[grow], s);
      }
#pragma unroll
      for (int n = 0; n < 4; ++n) {
        const size_t idx = grow * (size_t)N + cols[n];
        if (EPI == 3) {
          Cp[idx] = v[n] + extra[idx];
        } else if (EPI == 5) {
          ((u16*)Cv)[idx] = f2bf(v[n]);
        } else if (EPI == 6) {
          Cp[idx] = v[n];
        }
      }
    }
  }
}

// ---------------- attention with the faithful raw-reshape semantics ----------
// head h, key j in [0,32): kv position = 2h + j/16, d-slice = (j%16)*64 .. +64
// q applied here: q_eff[d] = qpre[d]*gq[d]*rsq_q*0.125 (rms of q folded)
__global__ __launch_bounds__(256) void attn_k(const u16* __restrict__ qf,
                                              const u16* __restrict__ kmat,
                                              const float* __restrict__ kssq,
                                              const u16* __restrict__ vmat,
                                              const float* __restrict__ gq,
                                              const float* __restrict__ qssq,
                                              u16* __restrict__ ao) {
  const int lb = blockIdx.x;
  const int t = threadIdx.x;
  const int wave = t >> 6, lane = t & 63;
  const int j = lane & 31, half = lane >> 5;
  const float rq = rsqrtf(qssq[lb] * (1.f / 1024.f) + 1e-6f) * 0.125f;
  __shared__ float po[64][17];
#pragma unroll
  for (int hi = 0; hi < 4; ++hi) {
    const int h = wave * 4 + hi;
    const int krow = lb * 32 + 2 * h + (j >> 4);
    const u16* kp = kmat + (size_t)krow * 1024 + (j & 15) * 64 + half * 32;
    const u16* qp = qf + (size_t)lb * 1024 + h * 64 + half * 32;
    const float* gqp = gq + h * 64 + half * 32;
    float s = 0.f;
#pragma unroll
    for (int cc = 0; cc < 4; ++cc) {
      s8v qv = *(const s8v*)(qp + cc * 8);
      s8v kv = *(const s8v*)(kp + cc * 8);
#pragma unroll
      for (int e = 0; e < 8; ++e)
        s += bf2f((u16)qv[e]) * gqp[cc * 8 + e] * bf2f((u16)kv[e]);
    }
    s += __shfl_xor(s, 32);
    s *= rsqrtf(kssq[krow] * (1.f / 1024.f) + 1e-6f) * rq;
    float mx = s;
#pragma unroll
    for (int m = 16; m >= 1; m >>= 1) mx = fmaxf(mx, __shfl_xor(mx, m));
    const float pe = __expf(s - mx);
    float sum = pe;
#pragma unroll
    for (int m = 16; m >= 1; m >>= 1) sum += __shfl_xor(sum, m);
    const float pr = pe / sum;
    float o = 0.f;
#pragma unroll
    for (int jj = 0; jj < 32; ++jj) {
      const int vrow = lb * 32 + 2 * h + (jj >> 4);
      const float vv = bf2f(vmat[(size_t)vrow * 1024 + (jj & 15) * 64 + lane]);
      o += __shfl(pr, jj) * vv;
    }
    po[lane][h] = o;  // hd = lane
  }
  __syncthreads();
  const int c = t * 4;
  u16x4 o4;
#pragma unroll
  for (int i = 0; i < 4; ++i) o4[i] = f2bf(po[(c + i) >> 4][(c + i) & 15]);
  *(u16x4*)(ao + (size_t)lb * 1024 + c) = o4;
}

// ------------- W2 split-K combine: out = p0 + p1 + b2[col] + resid -----------
__global__ __launch_bounds__(256) void combine_k(const float* __restrict__ p0,
                                                 const float* __restrict__ p1,
                                                 const float* __restrict__ b2,
                                                 const float* __restrict__ resid,
                                                 float* __restrict__ out) {
  const int i = blockIdx.x * 256 + threadIdx.x;  // float4 index
  float4 a = ((const float4*)p0)[i];
  float4 b = ((const float4*)p1)[i];
  float4 r = ((const float4*)resid)[i];
  float4 bb = ((const float4*)b2)[i & 255];
  float4 o;
  o.x = a.x + b.x + r.x + bb.x;
  o.y = a.y + b.y + r.y + bb.y;
  o.z = a.z + b.z + r.z + bb.z;
  o.w = a.w + b.w + r.w + bb.w;
  ((float4*)out)[i] = o;
}

// -----------------------------------------------------------------------------
extern "C" void kernel_launch(void* const* d_in, const int* in_sizes, int n_in,
                              void* d_out, int out_size, void* d_ws, size_t ws_size,
                              hipStream_t stream) {
  const float* query  = (const float*)d_in[0];
  const float* pf     = (const float*)d_in[1];
  const float* lnq_g  = (const float*)d_in[2];
  const float* lnq_b  = (const float*)d_in[3];
  const float* lnkv_g = (const float*)d_in[4];
  const float* lnkv_b = (const float*)d_in[5];
  const float* Wq     = (const float*)d_in[6];
  const float* bq     = (const float*)d_in[7];
  const float* Wk     = (const float*)d_in[8];
  const float* bk     = (const float*)d_in[9];
  const float* Wv     = (const float*)d_in[10];
  const float* bv     = (const float*)d_in[11];
  const float* rmsq_g = (const float*)d_in[12];
  const float* rmsk_g = (const float*)d_in[13];
  const float* Wo     = (const float*)d_in[14];
  const float* bo     = (const float*)d_in[15];
  const float* mlpn_g = (const float*)d_in[16];
  const float* mlpn_b = (const float*)d_in[17];
  const float* W1     = (const float*)d_in[18];
  const float* b1     = (const float*)d_in[19];
  const float* W2     = (const float*)d_in[20];
  const float* b2     = (const float*)d_in[21];
  float* out = (float*)d_out;

  char* p = (char*)d_ws;
  auto alloc = [&](size_t n) {
    char* r = p;
    p += (n + 255) & ~(size_t)255;
    return r;
  };

  u16* Wqt = (u16*)alloc((size_t)1024 * 1024 * 2);
  u16* KVt = (u16*)alloc((size_t)2048 * 1024 * 2);  // [Wk^T ; Wv^T]
  u16* Wot = (u16*)alloc((size_t)1024 * 1024 * 2);
  u16* W1t = (u16*)alloc((size_t)1024 * 4096 * 2);
  u16* W2t = (u16*)alloc((size_t)4096 * 1024 * 2);
  u16* qln = (u16*)alloc((size_t)4096 * 1024 * 2);
  u16* qpre = (u16*)alloc((size_t)4096 * 1024 * 2);
  float* qssq = (float*)alloc((size_t)4096 * 4);
  u16* attn_o = (u16*)alloc((size_t)4096 * 1024 * 2);
  float* outbuf = (float*)alloc((size_t)4096 * 1024 * 4);
  u16* hbuf = (u16*)alloc((size_t)4096 * 1024 * 2);
  u16* mid = (u16*)alloc((size_t)4096 * 4096 * 2);
  float* w2p = (float*)alloc((size_t)2 * 4096 * 1024 * 4);  // split-K partials

  // chunked KV pipeline buffers (NC chunks; chunk data stays L3-resident)
  const size_t used = (size_t)(p - (char*)d_ws);
  int NC = 4;
  while (NC < 64) {
    size_t rows_try = (size_t)131072 / NC;
    if (used + 3 * (rows_try * 2048 + 256) + rows_try * 4 + 256 <= ws_size) break;
    NC *= 2;
  }
  const size_t rows = (size_t)131072 / NC;
  u16* kvln = (u16*)alloc(rows * 2048);
  u16* kmat = (u16*)alloc(rows * 2048);
  u16* vmat = (u16*)alloc(rows * 2048);
  float* kssq = (float*)alloc(rows * 4);

  // weight transpose+convert: W[K][N] f32 -> Wt[N][K] bf16
  transpose_w<<<dim3(32, 32), 256, 0, stream>>>(Wq, Wqt, 1024, 1024);
  transpose_w<<<dim3(32, 32), 256, 0, stream>>>(Wk, KVt, 1024, 1024);
  transpose_w<<<dim3(32, 32), 256, 0, stream>>>(Wv, KVt + (size_t)1024 * 1024, 1024, 1024);
  transpose_w<<<dim3(32, 32), 256, 0, stream>>>(Wo, Wot, 1024, 1024);
  transpose_w<<<dim3(128, 32), 256, 0, stream>>>(W1, W1t, 1024, 4096);
  transpose_w<<<dim3(32, 128), 256, 0, stream>>>(W2, W2t, 4096, 1024);

  // q path: LN -> GEMM(Wq)+bq (epilogue: bf16 qpre + qssq atomics)
  ln_rows<<<4096, 256, 0, stream>>>(query, lnq_g, lnq_b, qln, qssq);
  gemm_bt<5><<<dim3(8, 32), 256, 0, stream>>>(qln, Wqt, bq, nullptr, qpre, nullptr,
                                              qssq, 4096, 1024, 1024);

  // kv path: chunked ln -> fused K+V gemm256 -> attn (chunk stays in L3)
  const int bpc = 4096 / NC;
  const int RB = (int)(rows / 256);
  for (int c = 0; c < NC; ++c) {
    ln_rows<<<(unsigned)rows, 256, 0, stream>>>(pf + (size_t)c * rows * 1024, lnkv_g,
                                                lnkv_b, kvln, kssq);
    gemm256<0, 1024><<<RB * 8, 512, 0, stream>>>(kvln, KVt, bk, bv, rmsk_g, kmat, vmat,
                                                 kssq, (int)rows, 2048, RB, 8);
    attn_k<<<bpc, 256, 0, stream>>>(qpre + (size_t)c * bpc * 1024, kmat, kssq, vmat,
                                    rmsq_g, qssq + (size_t)c * bpc,
                                    attn_o + (size_t)c * bpc * 1024);
  }

  // out = attn_o @ Wo + bo + query  (f32)
  gemm_bt<3><<<dim3(8, 32), 256, 0, stream>>>(attn_o, Wot, bo, nullptr, outbuf, query,
                                              nullptr, 4096, 1024, 1024);
  // h = LN(out)
  ln_rows<<<4096, 256, 0, stream>>>(outbuf, mlpn_g, mlpn_b, hbuf, nullptr);
  // mid = gelu(h @ W1 + b1)  -- 256^2 kernel, grid 16x16
  gemm256<1, 1024><<<16 * 16, 512, 0, stream>>>(hbuf, W1t, b1, nullptr, nullptr, mid,
                                                nullptr, nullptr, 4096, 4096, 16, 16);
  // final = mid @ W2 (split-K=2 partials) + b2 + out
  gemm_bt<6><<<dim3(8, 32, 2), 256, 0, stream>>>(mid, W2t, nullptr, nullptr, w2p,
                                                 nullptr, nullptr, 4096, 1024, 4096);
  combine_k<<<4096, 256, 0, stream>>>(w2p, w2p + (size_t)4096 * 1024, b2, outbuf, out);
}